// Round 10
// baseline (552.390 us; speedup 1.0000x reference)
//
#include <hip/hip_runtime.h>
#include <math.h>

#define NBATCH 16
#define SEQL   512
#define DIM    41
#define LDFLAT (SEQL*DIM)   // 20992
#define OBS    4096
#define DK     128
#define NH     4
#define DH     32

typedef short bf16x8 __attribute__((ext_vector_type(8)));
typedef short short8v __attribute__((ext_vector_type(8)));
typedef float floatx4 __attribute__((ext_vector_type(4)));

__device__ __forceinline__ short f2bf(float f) {
  union { float f; unsigned u; } v;
  v.f = f;
  unsigned r = (v.u + 0x7fffu + ((v.u >> 16) & 1u)) >> 16;
  return (short)r;
}
__device__ __forceinline__ float bf2f(short s) {
  union { unsigned u; float f; } v;
  v.u = ((unsigned)(unsigned short)s) << 16;
  return v.f;
}

// ---- R19: R15 base (458.2us anchor) + two-deep weight prefetch (A/C) ------
// R18 post-mortem: attn2+fusedC merge regressed 458->496 (serialized 4
// head-phases in 1024 blocks, lost attn2's 4096-block parallelism, Vtc
// scatter conflicts). Full R15 revert. R19's single change: A/C counters
// (Mfma 5%, VALU 12%, HBM 23%, occ 23%) say waves stall on staged-load
// waitcnt — per-phase cover (16 MFMA + epilogue ~300cy) < load latency
// (L2 ~200 / HBM ~900cy). Issue each weight-half's loads TWO phases ahead:
// load now spans 2 GEMM phases + a barrier before its ds_write. Buffer
// parity and barrier fencing unchanged; +16 VGPR peak (occupancy intact);
// vmcnt waits target loads older than intervening stores (safe ordering).

__device__ __forceinline__ int swz(int row, int col) {  // col in shorts
  return row * 128 + ((((col >> 3) ^ row) & 15) << 3) + (col & 7);
}

// ---- 256-thread half-weight staging (16KB: 64 rows x 128 k) ----
typedef struct { int4 v[4]; } WStageH;
__device__ __forceinline__ void stage_load_h(WStageH& s,
                                             const short* __restrict__ Wh,
                                             int tid) {
#pragma unroll
  for (int k = 0; k < 4; k++)
    s.v[k] = *(const int4*)&Wh[(size_t)tid * 8 + (size_t)k * 2048];
}
__device__ __forceinline__ void stage_write_h(short* Wl, const WStageH& s,
                                              int tid) {
#pragma unroll
  for (int k = 0; k < 4; k++) {
    int i = tid * 8 + k * 2048;           // < 8192
    *(int4*)&Wl[swz(i >> 7, i & 127)] = s.v[k];
  }
}
// ---- 1024-thread full-weight staging (32KB) ----
typedef struct { int4 v[2]; } WStageF;
__device__ __forceinline__ void stage_load_f(WStageF& s,
                                             const short* __restrict__ W,
                                             int tid) {
#pragma unroll
  for (int k = 0; k < 2; k++)
    s.v[k] = *(const int4*)&W[(size_t)tid * 8 + (size_t)k * 8192];
}
__device__ __forceinline__ void stage_write_f(short* Wl, const WStageF& s,
                                              int tid) {
#pragma unroll
  for (int k = 0; k < 2; k++) {
    int i = tid * 8 + k * 8192;           // < 16384
    *(int4*)&Wl[swz(i >> 7, i & 127)] = s.v[k];
  }
}

// 4-nt GEMM against a 64-row weight buffer (one half)
__device__ __forceinline__ void gemm4_s(const short* Wl, const bf16x8 af[4],
                                        int lm, int quad, floatx4 acc[4]) {
#pragma unroll
  for (int nt = 0; nt < 4; nt++) acc[nt] = (floatx4){0.f, 0.f, 0.f, 0.f};
#pragma unroll
  for (int kc = 0; kc < 4; kc++) {
    bf16x8 a = af[kc];
#pragma unroll
    for (int nt = 0; nt < 4; nt++) {
      bf16x8 b = *(const bf16x8*)&Wl[swz(nt * 16 + lm, kc * 32 + quad * 8)];
      acc[nt] = __builtin_amdgcn_mfma_f32_16x16x32_bf16(a, b, acc[nt], 0, 0, 0);
    }
  }
}
// 2-nt GEMM against a full 128-row buffer, col-quarter colq
__device__ __forceinline__ void gemm2_s(const short* Wl, const bf16x8 af[4],
                                        int colq, int lm, int quad,
                                        floatx4 acc[2]) {
#pragma unroll
  for (int nt = 0; nt < 2; nt++) acc[nt] = (floatx4){0.f, 0.f, 0.f, 0.f};
#pragma unroll
  for (int kc = 0; kc < 4; kc++) {
    bf16x8 a = af[kc];
#pragma unroll
    for (int nt = 0; nt < 2; nt++) {
      bf16x8 b = *(const bf16x8*)&Wl[swz(colq * 32 + nt * 16 + lm,
                                         kc * 32 + quad * 8)];
      acc[nt] = __builtin_amdgcn_mfma_f32_16x16x32_bf16(a, b, acc[nt], 0, 0, 0);
    }
  }
}
__device__ __forceinline__ void load_af_s(const short* Xl, int strip, int lm,
                                          int quad, bf16x8 af[4]) {
#pragma unroll
  for (int kc = 0; kc < 4; kc++)
    af[kc] = *(const bf16x8*)&Xl[swz(strip * 16 + lm, kc * 32 + quad * 8)];
}
// stage bias-added bf16 half-result (wave-local rows), cols colbase..+63
__device__ __forceinline__ void store_sl4(short* Sl, const floatx4 acc[4],
                                          const float* __restrict__ bias,
                                          int wv, int lm, int quad,
                                          int colbase) {
#pragma unroll
  for (int nt = 0; nt < 4; nt++) {
    int col = colbase + nt * 16 + lm;
    float bn = bias[col];
#pragma unroll
    for (int r = 0; r < 4; r++)
      Sl[swz(wv * 16 + quad * 4 + r, col)] = f2bf(acc[nt][r] + bn);
  }
}
// write Sl rows rb..rb+63 to head-split out (wave-local rows: rr=tid>>2)
__device__ __forceinline__ void write_hs_s(const short* Sl,
                                           short* __restrict__ out, int rb,
                                           int nshift, int tid) {
  int rr = tid >> 2, hh = tid & 3;
  int r = rb + rr;
  int bb = r >> nshift, nn = r & ((1 << nshift) - 1);
  size_t o = (((size_t)(bb * NH + hh) << nshift) + nn) * 32;
#pragma unroll
  for (int j = 0; j < 4; j++)
    *(int4*)&out[o + j * 8] = *(int4*)&Sl[swz(rr, hh * 32 + j * 8)];
}
// 1024-thread quarter write: wave (strip,colq) writes its own 16 rows x head
__device__ __forceinline__ void write_hs_q(const short* Sl,
                                           short* __restrict__ out, int rb,
                                           int nshift, int strip, int colq,
                                           int lane) {
  int rr = strip * 16 + (lane >> 2);
  int r = rb + rr;
  int bb = r >> nshift, nn = r & ((1 << nshift) - 1);
  size_t o = (((size_t)(bb * NH + colq) << nshift) + nn) * 32 + (lane & 3) * 8;
  *(int4*)&out[o] = *(const int4*)&Sl[swz(rr, colq * 32 + (lane & 3) * 8)];
}

// ---------------------------------------------------------------------------
// Kernel: merged weight-prep (blocks 0..23) + stable-order scan (blocks 24..39)
// ---------------------------------------------------------------------------
__global__ __launch_bounds__(1024) void prep_build_kernel(
    const float* __restrict__ q0w, const float* __restrict__ k0w,
    const float* __restrict__ v0w, const float* __restrict__ o0w,
    const float* __restrict__ q1w, const float* __restrict__ k1w,
    const float* __restrict__ v1w, const float* __restrict__ o1w,
    short* __restrict__ Wt,
    const float* __restrict__ mask, int* __restrict__ order,
    float* __restrict__ mk_out, float* __restrict__ mk_out2) {
  __shared__ float Tl[128 * 132];
  __shared__ int wsums[16];
  __shared__ int s_total_ones;
  __shared__ int s_chunk_ones;
  __shared__ int s_ones_base;
  __shared__ int s_zeros_base;
  int tid = threadIdx.x;

  if (blockIdx.x < 24) {
    int id = blockIdx.x, l = id >> 3, wi = id & 7;
    const float* s;
    switch (wi) {
      case 0: s = q0w; break; case 1: s = k0w; break;
      case 2: s = v0w; break; case 3: s = o0w; break;
      case 4: s = q1w; break; case 5: s = k1w; break;
      case 6: s = v1w; break; default: s = o1w; break;
    }
    s += (size_t)l * 16384;
    for (int i = tid * 4; i < 16384; i += 4096) {
      int k = i >> 7, n = i & 127;
      float4 x = *(const float4*)&s[i];
      Tl[k * 132 + n + 0] = x.x; Tl[k * 132 + n + 1] = x.y;
      Tl[k * 132 + n + 2] = x.z; Tl[k * 132 + n + 3] = x.w;
    }
    __syncthreads();
    short* dst = Wt + (size_t)id * 16384;
    int n = tid >> 3, k0 = (tid & 7) * 16;
    for (int jc = 0; jc < 2; jc++) {
      short8v t;
#pragma unroll
      for (int j = 0; j < 8; j++) t[j] = f2bf(Tl[(k0 + jc * 8 + j) * 132 + n]);
      *(short8v*)&dst[n * 128 + k0 + jc * 8] = t;
    }
    return;
  }

  int b = blockIdx.x - 24;
  const float* m = mask + (size_t)b * LDFLAT;
  int lane = tid & 63, w = tid >> 6;

  int cnt = 0;
  for (int j = tid; j < LDFLAT; j += 1024) cnt += (m[j] > 0.f) ? 1 : 0;
  for (int off = 32; off > 0; off >>= 1) cnt += __shfl_xor(cnt, off);
  if (lane == 0) wsums[w] = cnt;
  __syncthreads();
  if (tid == 0) {
    int t = 0;
    for (int i = 0; i < 16; i++) t += wsums[i];
    s_total_ones = t; s_ones_base = 0; s_zeros_base = 0;
  }
  __syncthreads();
  int total_ones = s_total_ones;

  for (int c0 = 0; c0 < LDFLAT; c0 += 1024) {
    __syncthreads();
    int j = c0 + tid;
    bool valid = (j < LDFLAT);
    float mv = valid ? m[j] : 0.f;
    int one = (valid && mv > 0.f) ? 1 : 0;
    int v = one;
    for (int off = 1; off < 64; off <<= 1) {
      int t = __shfl_up(v, (unsigned)off);
      if (lane >= off) v += t;
    }
    if (lane == 63) wsums[w] = v;
    __syncthreads();
    if (tid == 0) {
      int run = 0;
      for (int i = 0; i < 16; i++) { int t = wsums[i]; wsums[i] = run; run += t; }
      s_chunk_ones = run;
    }
    __syncthreads();
    int ones_before = (v - one) + wsums[w];
    int ob = s_ones_base, zb = s_zeros_base, chunk_ones = s_chunk_ones;
    int rem = LDFLAT - c0;
    int chunk_valid = rem < 1024 ? rem : 1024;
    int valid_before = tid < rem ? tid : rem;
    if (valid) {
      int pos = one ? (ob + ones_before)
                    : (total_ones + zb + (valid_before - ones_before));
      if (pos < OBS) {
        order[b * OBS + pos] = j;
        mk_out[b * OBS + pos] = mv;
        mk_out2[b * OBS + pos] = mv;
      }
    }
    __syncthreads();
    if (tid == 0) {
      s_ones_base = ob + chunk_ones;
      s_zeros_base = zb + (chunk_valid - chunk_ones);
    }
  }
}

// ---------------------------------------------------------------------------
// Kernel: fusedA — embed (layer-0 Z) + K0/V0/Q1 projections (blocks 0..1023)
//                + ind-point Q projections for all 3 layers (blocks 1024..1029)
// R13 structure + R19 two-deep weight prefetch.
// ---------------------------------------------------------------------------
__global__ __launch_bounds__(256, 3) void fusedA_kernel(
    const int* __restrict__ order, const float* __restrict__ mk_g,
    const float* __restrict__ cx, const float* __restrict__ value,
    const float* __restrict__ iff_w, const float* __restrict__ iff_b,
    float* __restrict__ Z,
    const short* __restrict__ Wk, const float* __restrict__ kbias,
    short* __restrict__ Kb,
    const short* __restrict__ Wv, const float* __restrict__ vbias,
    short* __restrict__ Vb,
    const short* __restrict__ Wq, const float* __restrict__ qbias,
    short* __restrict__ Qb,
    const float* __restrict__ indp, const short* __restrict__ WtAll,
    const float* __restrict__ q0b_all, short* __restrict__ qh_b) {
  __shared__ __align__(16) short Xl[64 * 128];
  __shared__ __align__(16) short WlA[64 * 128];
  __shared__ __align__(16) short WlB[64 * 128];
  int tid = threadIdx.x;
  int wv = tid >> 6, lane = tid & 63, lm = lane & 15, quad = lane >> 4;
  int r_l = lane >> 2, seg = lane & 3;
  int lrow = wv * 16 + r_l;      // wave-local row this lane helps fill

  if (blockIdx.x >= 1024) {
    // ---- qh_proj path: both halves staged upfront, 1 barrier ----
    int id = blockIdx.x - 1024;
    int l = id >> 1, rbq = (id & 1) * 64;
    const float* X = indp + (size_t)l * 16384 + (size_t)rbq * 128;
    const short* W = WtAll + (size_t)(l * 8) * 16384;  // q0w^T
    const float* bias = q0b_all + (size_t)l * 128;
    short* out = qh_b + (size_t)l * 16384;
    WStageH sA, sB;
    stage_load_h(sA, W, tid);
    stage_load_h(sB, W + 8192, tid);
    const float* Xr = X + (size_t)lrow * 128;
#pragma unroll
    for (int jj = 0; jj < 8; jj++) {
      int col = seg * 32 + jj * 4;
      float4 x = *(const float4*)&Xr[col];
      *(short4*)&Xl[swz(lrow, col)] =
          make_short4(f2bf(x.x), f2bf(x.y), f2bf(x.z), f2bf(x.w));
    }
    stage_write_h(WlA, sA, tid);
    stage_write_h(WlB, sB, tid);
    __syncthreads();
    bf16x8 af[4];
    load_af_s(Xl, wv, lm, quad, af);
    floatx4 acc[4];
    gemm4_s(WlA, af, lm, quad, acc);
    store_sl4(Xl, acc, bias, wv, lm, quad, 0);
    gemm4_s(WlB, af, lm, quad, acc);
    store_sl4(Xl, acc, bias, wv, lm, quad, 64);
    write_hs_s(Xl, out, rbq, 7, tid);
    return;
  }

  int rb = blockIdx.x * 64;
  WStageH s0; stage_load_h(s0, Wk, tid);          // depth-2 pipeline head
  WStageH s1; stage_load_h(s1, Wk + 8192, tid);
  int grow = rb + lrow;
  int bb = grow >> 12;
  int j = order[grow];               // 4 lanes/row share -> broadcast-coalesced
  int l = j / DIM, d = j - l * DIM;
  float t = cx[bb * SEQL + l];
  float u = value[(size_t)bb * LDFLAT + j];
  float mkv = mk_g[grow];
#pragma unroll
  for (int jj = 0; jj < 8; jj++) {
    int col = seg * 32 + jj * 4;
    float4 w0 = *(const float4*)&iff_w[d * DK + col];
    float4 w1 = *(const float4*)&iff_w[41 * DK + col];
    float4 w2 = *(const float4*)&iff_w[42 * DK + col];
    float4 b4 = *(const float4*)&iff_b[col];
    float4 z;
    z.x = fmaxf(w0.x + t * w1.x + u * w2.x + b4.x, 0.f) * mkv;
    z.y = fmaxf(w0.y + t * w1.y + u * w2.y + b4.y, 0.f) * mkv;
    z.z = fmaxf(w0.z + t * w1.z + u * w2.z + b4.z, 0.f) * mkv;
    z.w = fmaxf(w0.w + t * w1.w + u * w2.w + b4.w, 0.f) * mkv;
    *(float4*)&Z[(size_t)grow * DK + col] = z;
    *(short4*)&Xl[swz(lrow, col)] =
        make_short4(f2bf(z.x), f2bf(z.y), f2bf(z.z), f2bf(z.w));
  }
  stage_write_h(WlA, s0, tid);
  __syncthreads();   // B1: Xl(embed) + WlA(Wk0)
  WStageH s2; stage_load_h(s2, Wv, tid);
  bf16x8 af[4];
  load_af_s(Xl, wv, lm, quad, af);   // af cached for all GEMMs
  floatx4 acc[4];
  gemm4_s(WlA, af, lm, quad, acc);
  store_sl4(Xl, acc, kbias, wv, lm, quad, 0);
  stage_write_h(WlB, s1, tid);
  __syncthreads();   // B2: WlB(Wk1)
  WStageH s3; stage_load_h(s3, Wv + 8192, tid);
  gemm4_s(WlB, af, lm, quad, acc);
  store_sl4(Xl, acc, kbias, wv, lm, quad, 64);
  write_hs_s(Xl, Kb, rb, 12, tid);
  stage_write_h(WlA, s2, tid);
  __syncthreads();   // B3: WlA(Wv0)
  WStageH s4; stage_load_h(s4, Wq, tid);
  gemm4_s(WlA, af, lm, quad, acc);
  store_sl4(Xl, acc, vbias, wv, lm, quad, 0);
  stage_write_h(WlB, s3, tid);
  __syncthreads();   // B4: WlB(Wv1)
  WStageH s5; stage_load_h(s5, Wq + 8192, tid);
  gemm4_s(WlB, af, lm, quad, acc);
  store_sl4(Xl, acc, vbias, wv, lm, quad, 64);
  write_hs_s(Xl, Vb, rb, 12, tid);
  stage_write_h(WlA, s4, tid);
  __syncthreads();   // B5: WlA(Wq0)
  gemm4_s(WlA, af, lm, quad, acc);
  store_sl4(Xl, acc, qbias, wv, lm, quad, 0);
  stage_write_h(WlB, s5, tid);
  __syncthreads();   // B6: WlB(Wq1)
  gemm4_s(WlB, af, lm, quad, acc);
  store_sl4(Xl, acc, qbias, wv, lm, quad, 64);
  write_hs_s(Xl, Qb, rb, 12, tid);
}

// ---------------------------------------------------------------------------
// Kernel: MAB1 attention (bf16), flash over 8 key splits. grid (64, 8).
// R15: K/V chunk register prefetch; Vtc stride 74 (bank-conflict-free).
// ---------------------------------------------------------------------------
__global__ __launch_bounds__(256) void attn1_kernel(
    const short* __restrict__ Qh,   // (NH,128,32) bf16, layer base
    const short* __restrict__ Kh, const short* __restrict__ Vh,
    const float* __restrict__ mk,
    float* __restrict__ Opart, float* __restrict__ mpart,
    float* __restrict__ lpart) {
  __shared__ __align__(16) short Ql[128 * 40];
  __shared__ __align__(16) short Kc[64 * 40];
  __shared__ __align__(16) short Vtc[32 * 74];
  __shared__ __align__(16) short Pl[128 * 72];
  __shared__ float mkc[64];
  int bh = blockIdx.x;
  int b = bh >> 2, h = bh & 3;
  int ks = blockIdx.y;
  int tid = threadIdx.x;
  int wv = tid >> 6, lane = tid & 63, lm = lane & 15, quad = lane >> 4;

  const float scale = 0.08838834764831845f;
  const short* kbase = Kh + ((size_t)bh * OBS + ks * 512) * 32;
  const short* vbase = Vh + ((size_t)bh * OBS + ks * 512) * 32;
  const float* mkb = mk + (size_t)b * OBS + ks * 512;

  // prefetch chunk 0 K/V + mk into registers (overlaps Q staging)
  int i0 = tid * 8;
  int r0 = i0 >> 5, cv = i0 & 31;
  int4 kreg = *(const int4*)&kbase[i0];
  int4 vreg = *(const int4*)&vbase[i0];
  float mreg = (tid < 64) ? mkb[tid] : 0.f;

  const short* qbg = Qh + (size_t)h * 128 * 32;
  for (int i = tid * 8; i < 128 * 32; i += 2048) {
    int r = i >> 5, c = i & 31;
    *(int4*)&Ql[r * 40 + c] = *(const int4*)&qbg[i];
  }
  __syncthreads();
  bf16x8 aq[2];
  aq[0] = *(bf16x8*)&Ql[(wv * 32 + lm) * 40 + quad * 8];
  aq[1] = *(bf16x8*)&Ql[(wv * 32 + 16 + lm) * 40 + quad * 8];

  float m_i[2][4], l_i[2][4];
  floatx4 oacc[2][2];
#pragma unroll
  for (int mt = 0; mt < 2; mt++) {
#pragma unroll
    for (int r = 0; r < 4; r++) { m_i[mt][r] = -1e30f; l_i[mt][r] = 0.f; }
    oacc[mt][0] = (floatx4){0.f, 0.f, 0.f, 0.f};
    oacc[mt][1] = (floatx4){0.f, 0.f, 0.f, 0.f};
  }

  for (int ch = 0; ch < 8; ch++) {
    __syncthreads();   // prev chunk's Kc/Vtc reads done
    *(int4*)&Kc[r0 * 40 + cv] = kreg;
    {
      short* vv = (short*)&vreg;
#pragma unroll
      for (int j = 0; j < 8; j++) Vtc[(cv + j) * 74 + r0] = vv[j];
    }
    if (tid < 64) mkc[tid] = mreg;
    if (ch < 7) {      // issue next chunk's loads; latency hides under compute
      kreg = *(const int4*)&kbase[(ch + 1) * 2048 + i0];
      vreg = *(const int4*)&vbase[(ch + 1) * 2048 + i0];
      if (tid < 64) mreg = mkb[(ch + 1) * 64 + tid];
    }
    __syncthreads();   // Kc/Vtc/mkc ready

    floatx4 sf[2][4];
#pragma unroll
    for (int nt = 0; nt < 4; nt++) {
      bf16x8 bfrag = *(bf16x8*)&Kc[(nt * 16 + lm) * 40 + quad * 8];
      floatx4 z = {0.f, 0.f, 0.f, 0.f};
      sf[0][nt] = __builtin_amdgcn_mfma_f32_16x16x32_bf16(aq[0], bfrag, z, 0, 0, 0);
      sf[1][nt] = __builtin_amdgcn_mfma_f32_16x16x32_bf16(aq[1], bfrag, z, 0, 0, 0);
    }
#pragma unroll
    for (int nt = 0; nt < 4; nt++) {
      float mkv = mkc[nt * 16 + lm];
      bool ok = mkv > 0.f;
#pragma unroll
      for (int mt = 0; mt < 2; mt++)
#pragma unroll
        for (int r = 0; r < 4; r++)
          sf[mt][nt][r] = ok ? sf[mt][nt][r] * scale : -1e10f;
    }
#pragma unroll
    for (int mt = 0; mt < 2; mt++) {
#pragma unroll
      for (int r = 0; r < 4; r++) {
        float mx = fmaxf(fmaxf(sf[mt][0][r], sf[mt][1][r]),
                         fmaxf(sf[mt][2][r], sf[mt][3][r]));
        mx = fmaxf(mx, __shfl_xor(mx, 1));
        mx = fmaxf(mx, __shfl_xor(mx, 2));
        mx = fmaxf(mx, __shfl_xor(mx, 4));
        mx = fmaxf(mx, __shfl_xor(mx, 8));
        float mn = fmaxf(m_i[mt][r], mx);
        float al = __expf(m_i[mt][r] - mn);
        float ps = 0.f;
#pragma unroll
        for (int nt = 0; nt < 4; nt++) {
          float p = __expf(sf[mt][nt][r] - mn);
          sf[mt][nt][r] = p;
          ps += p;
        }
        ps += __shfl_xor(ps, 1);
        ps += __shfl_xor(ps, 2);
        ps += __shfl_xor(ps, 4);
        ps += __shfl_xor(ps, 8);
        l_i[mt][r] = l_i[mt][r] * al + ps;
        m_i[mt][r] = mn;
        oacc[mt][0] *= al;
        oacc[mt][1] *= al;
      }
    }
#pragma unroll
    for (int mt = 0; mt < 2; mt++)
#pragma unroll
      for (int nt = 0; nt < 4; nt++)
#pragma unroll
        for (int r = 0; r < 4; r++)
          Pl[(wv * 32 + mt * 16 + quad * 4 + r) * 72 + nt * 16 + lm] =
              f2bf(sf[mt][nt][r]);
#pragma unroll
    for (int kc = 0; kc < 2; kc++) {
      bf16x8 vf0 = *(bf16x8*)&Vtc[lm * 74 + kc * 32 + quad * 8];
      bf16x8 vf1 = *(bf16x8*)&Vtc[(16 + lm) * 74 + kc * 32 + quad * 8];
#pragma unroll
      for (int mt = 0; mt < 2; mt++) {
        bf16x8 pf = *(bf16x8*)&Pl[(wv * 32 + mt * 16 + lm) * 72 + kc * 32 + quad * 8];
        oacc[mt][0] = __builtin_amdgcn_mfma_f32_16x16x32_bf16(pf, vf0, oacc[mt][0], 0, 0, 0);
        oacc[mt][1] = __builtin_amdgcn_mfma_f32_16x16x32_bf16(pf, vf1, oacc[mt][1], 0, 0, 0);
      }
    }
  }
  float* ob = Opart + (size_t)(ks * 64 + bh) * 128 * 32;
#pragma unroll
  for (int mt = 0; mt < 2; mt++) {
#pragma unroll
    for (int r = 0; r < 4; r++) {
      int row = wv * 32 + mt * 16 + quad * 4 + r;
      ob[(size_t)row * 32 + lm] = oacc[mt][0][r];
      ob[(size_t)row * 32 + 16 + lm] = oacc[mt][1][r];
      if (lm == 0) {
        mpart[(size_t)(ks * 64 + bh) * 128 + row] = m_i[mt][r];
        lpart[(size_t)(ks * 64 + bh) * 128 + row] = l_i[mt][r];
      }
    }
  }
}

// ---------------------------------------------------------------------------
// Kernel: fusedB — attn1 combine + fc_o + K1/V1 projections. grid 32 x 1024.
// 16 waves (4 row-strips x 4 col-quarters); full-weight dbuf. (R15 version)
// ---------------------------------------------------------------------------
__global__ __launch_bounds__(1024) void fusedB_kernel(
    const float* __restrict__ Opart, const float* __restrict__ mpart,
    const float* __restrict__ lpart, const short* __restrict__ qh,
    const short* __restrict__ Wo, const float* __restrict__ obias,
    const short* __restrict__ Wk, const float* __restrict__ kbias,
    const short* __restrict__ Wv, const float* __restrict__ vbias,
    short* __restrict__ khb, short* __restrict__ vhb) {
  __shared__ __align__(16) short Xl[64 * 128];
  __shared__ __align__(16) short WlA[128 * 128];
  __shared__ __align__(16) short WlB[128 * 128];
  int tid = threadIdx.x;
  int rb = blockIdx.x * 64;           // row in 2048 = b*128 + n
  int b = rb >> 7, n0 = rb & 127;
  int wv = tid >> 6, lane = tid & 63, lm = lane & 15, quad = lane >> 4;
  int strip = wv & 3, colq = wv >> 2;
  WStageF sWo; stage_load_f(sWo, Wo, tid);
  // combine: 256 (row,head) pairs x 8 lanes = 2 passes of 1024
#pragma unroll
  for (int p = 0; p < 2; p++) {
    int slot = p * 1024 + tid;
    int pair = slot >> 3;
    int hh = pair & 3, rr = pair >> 2;
    int c4 = (slot & 7) * 4;
    int n = n0 + rr;
    int bh = b * 4 + hh;
    float mv[8], lv[8], m = -1e30f;
#pragma unroll
    for (int s = 0; s < 8; s++) {
      mv[s] = mpart[(size_t)(s * 64 + bh) * 128 + n];
      lv[s] = lpart[(size_t)(s * 64 + bh) * 128 + n];
      m = fmaxf(m, mv[s]);
    }
    float l = 0.f, oa0 = 0.f, oa1 = 0.f, oa2 = 0.f, oa3 = 0.f;
#pragma unroll
    for (int s = 0; s < 8; s++) {
      float w = __expf(mv[s] - m);
      l += lv[s] * w;
      float4 v = *(const float4*)&Opart[((size_t)(s * 64 + bh) * 128 + n) * 32 + c4];
      oa0 += v.x * w; oa1 += v.y * w; oa2 += v.z * w; oa3 += v.w * w;
    }
    float li = 1.f / l;
    int2 qi = *(const int2*)&qh[((size_t)hh * 128 + n) * 32 + c4];
    const short* qs = (const short*)&qi;
    short4 o4;
    o4.x = f2bf(bf2f(qs[0]) + oa0 * li);
    o4.y = f2bf(bf2f(qs[1]) + oa1 * li);
    o4.z = f2bf(bf2f(qs[2]) + oa2 * li);
    o4.w = f2bf(bf2f(qs[3]) + oa3 * li);
    *(short4*)&Xl[swz(rr, hh * 32 + c4)] = o4;
  }
  stage_write_f(WlA, sWo, tid);
  __syncthreads();   // B1: Xl(O) + WlA(Wo)
  bf16x8 afO[4];
  load_af_s(Xl, strip, lm, quad, afO);
  __syncthreads();   // B1b: all O reads done before H writes
  WStageF sWk; stage_load_f(sWk, Wk, tid);
  floatx4 acc[2];
  gemm2_s(WlA, afO, colq, lm, quad, acc);
  // H = O + relu(acc + bias): in-place on this wave's (strip,colq) quarter
#pragma unroll
  for (int nt = 0; nt < 2; nt++) {
    int col = colq * 32 + nt * 16 + lm;
    float bn = obias[col];
#pragma unroll
    for (int r = 0; r < 4; r++) {
      int row = strip * 16 + quad * 4 + r;
      float ov = bf2f(Xl[swz(row, col)]);
      Xl[swz(row, col)] = f2bf(ov + fmaxf(acc[nt][r] + bn, 0.f));
    }
  }
  stage_write_f(WlB, sWk, tid);
  __syncthreads();   // B2: Xl(H) complete + WlB(Wk)
  bf16x8 afH[4];
  load_af_s(Xl, strip, lm, quad, afH);
  __syncthreads();   // B2b: all H reads done before K-result writes
  WStageF sWv; stage_load_f(sWv, Wv, tid);
  gemm2_s(WlB, afH, colq, lm, quad, acc);
#pragma unroll
  for (int nt = 0; nt < 2; nt++) {
    int col = colq * 32 + nt * 16 + lm;
    float bn = kbias[col];
#pragma unroll
    for (int r = 0; r < 4; r++)
      Xl[swz(strip * 16 + quad * 4 + r, col)] = f2bf(acc[nt][r] + bn);
  }
  write_hs_q(Xl, khb, rb, 7, strip, colq, lane);   // wave-local quarter
  stage_write_f(WlA, sWv, tid);
  __syncthreads();   // B3: WlA(Wv); all khb reads done before V writes
  gemm2_s(WlA, afH, colq, lm, quad, acc);
#pragma unroll
  for (int nt = 0; nt < 2; nt++) {
    int col = colq * 32 + nt * 16 + lm;
    float bn = vbias[col];
#pragma unroll
    for (int r = 0; r < 4; r++)
      Xl[swz(strip * 16 + quad * 4 + r, col)] = f2bf(acc[nt][r] + bn);
  }
  write_hs_q(Xl, vhb, rb, 7, strip, colq, lane);
}

// ---------------------------------------------------------------------------
// Kernel: MAB2 attention, register softmax. grid (64, 64). LDS ~42 KB.
// ---------------------------------------------------------------------------
__global__ __launch_bounds__(256) void attn2_kernel(
    const short* __restrict__ Qh, const short* __restrict__ Kh,
    const short* __restrict__ Vh, short* __restrict__ O) {
  __shared__ __align__(16) short Kl[128 * 40];
  __shared__ __align__(16) short Vt[32 * 136];
  __shared__ __align__(16) short Ql[64 * 40];
  __shared__ __align__(16) short Pl[64 * 136];
  int bh = blockIdx.x;
  int b = bh >> 2, h = bh & 3;
  int q0 = blockIdx.y * 64;
  int tid = threadIdx.x;
  int wv = tid >> 6, lane = tid & 63, lm = lane & 15, quad = lane >> 4;
  const short* kb = Kh + (size_t)bh * 128 * 32;
  const short* vb = Vh + (size_t)bh * 128 * 32;
  const short* qb = Qh + ((size_t)bh * OBS + q0) * 32;

  for (int i = tid * 8; i < 128 * 32; i += 2048) {
    int r = i >> 5, c = i & 31;
    *(int4*)&Kl[r * 40 + c] = *(const int4*)&kb[i];
  }
  for (int i = tid * 8; i < 64 * 32; i += 2048) {
    int r = i >> 5, c = i & 31;
    *(int4*)&Ql[r * 40 + c] = *(const int4*)&qb[i];
  }
  for (int i = tid * 8; i < 128 * 32; i += 2048) {
    int r = i >> 5, c = i & 31;
    int4 vv4 = *(const int4*)&vb[i];
    short* vv = (short*)&vv4;
#pragma unroll
    for (int j = 0; j < 8; j++) Vt[(c + j) * 136 + r] = vv[j];
  }
  __syncthreads();

  const float scale = 0.08838834764831845f;
  bf16x8 afrag = *(bf16x8*)&Ql[(wv * 16 + lm) * 40 + quad * 8];
  floatx4 sf[8];
#pragma unroll
  for (int nt = 0; nt < 8; nt++) {
    bf16x8 bfrag = *(bf16x8*)&Kl[(nt * 16 + lm) * 40 + quad * 8];
    floatx4 z = {0.f, 0.f, 0.f, 0.f};
    sf[nt] = __builtin_amdgcn_mfma_f32_16x16x32_bf16(afrag, bfrag, z, 0, 0, 0);
  }
#pragma unroll
  for (int nt = 0; nt < 8; nt++) sf[nt] *= scale;
  float linv[4];
#pragma unroll
  for (int r = 0; r < 4; r++) {
    float mx = sf[0][r];
#pragma unroll
    for (int nt = 1; nt < 8; nt++) mx = fmaxf(mx, sf[nt][r]);
    mx = fmaxf(mx, __shfl_xor(mx, 1));
    mx = fmaxf(mx, __shfl_xor(mx, 2));
    mx = fmaxf(mx, __shfl_xor(mx, 4));
    mx = fmaxf(mx, __shfl_xor(mx, 8));
    float sum = 0.f;
#pragma unroll
    for (int nt = 0; nt < 8; nt++) {
      float p = __expf(sf[nt][r] - mx);
      sf[nt][r] = p;
      sum += p;
    }
    sum += __shfl_xor(sum, 1);
    sum += __shfl_xor(sum, 2);
    sum += __shfl_xor(sum, 4);
    sum += __shfl_xor(sum, 8);
    linv[r] = 1.f / sum;
  }
#pragma unroll
  for (int nt = 0; nt < 8; nt++)
#pragma unroll
    for (int r = 0; r < 4; r++)
      Pl[(wv * 16 + quad * 4 + r) * 136 + nt * 16 + lm] = f2bf(sf[nt][r]);

  floatx4 oacc[2] = {{0.f, 0.f, 0.f, 0.f}, {0.f, 0.f, 0.f, 0.f}};
#pragma unroll
  for (int kc = 0; kc < 4; kc++) {
    bf16x8 pf = *(bf16x8*)&Pl[(wv * 16 + lm) * 136 + kc * 32 + quad * 8];
#pragma unroll
    for (int nt2 = 0; nt2 < 2; nt2++) {
      bf16x8 vf = *(bf16x8*)&Vt[(nt2 * 16 + lm) * 136 + kc * 32 + quad * 8];
      oacc[nt2] = __builtin_amdgcn_mfma_f32_16x16x32_bf16(pf, vf, oacc[nt2], 0, 0, 0);
    }
  }
  // stage O+Q residual in Pl rows (wave-local), then coalesced int4 store
  short* Ol = Pl;
#pragma unroll
  for (int nt2 = 0; nt2 < 2; nt2++) {
#pragma unroll
    for (int r = 0; r < 4; r++) {
      int qrow = wv * 16 + quad * 4 + r;
      float q = bf2f(Ql[qrow * 40 + nt2 * 16 + lm]);
      Ol[qrow * 136 + nt2 * 16 + lm] = f2bf(q + oacc[nt2][r] * linv[r]);
    }
  }
  int rr = tid >> 2, seg = tid & 3;      // wave-local Ol rows
  size_t o = ((size_t)b * OBS + q0 + rr) * 128 + h * 32 + seg * 8;
  *(int4*)&O[o] = *(int4*)&Ol[rr * 136 + seg * 8];
}

// ---------------------------------------------------------------------------
// Kernel: fusedC — fc_o + residual Z update + next layer's K0/V0/Q1.
// grid 1024 (64 rows). Wk==null => last layer (no projections).
// R13 structure + R19 two-deep weight prefetch.
// ---------------------------------------------------------------------------
__global__ __launch_bounds__(256, 3) void fusedC_kernel(
    const short* __restrict__ Ob, const short* __restrict__ Wo,
    const float* __restrict__ obias, const float* __restrict__ mk,
    const float* __restrict__ Zin, float* __restrict__ Zout,
    const short* __restrict__ Wk, const float* __restrict__ kbias,
    short* __restrict__ Kb,
    const short* __restrict__ Wv, const float* __restrict__ vbias,
    short* __restrict__ Vb,
    const short* __restrict__ Wq, const float* __restrict__ qbias,
    short* __restrict__ Qb) {
  __shared__ __align__(16) short Xl[64 * 128];
  __shared__ __align__(16) short WlA[64 * 128];
  __shared__ __align__(16) short WlB[64 * 128];
  int tid = threadIdx.x;
  int rb = blockIdx.x * 64;
  int wv = tid >> 6, lane = tid & 63, lm = lane & 15, quad = lane >> 4;

  WStageH s0; stage_load_h(s0, Wo, tid);          // depth-2 pipeline head
  WStageH s1; stage_load_h(s1, Wo + 8192, tid);
  bf16x8 afO[4];
  {
    const short* arow = Ob + (size_t)(rb + wv * 16 + lm) * 128;
#pragma unroll
    for (int kc = 0; kc < 4; kc++) {
      afO[kc] = *(const bf16x8*)&arow[kc * 32 + quad * 8];
      *(bf16x8*)&Xl[swz(wv * 16 + lm, kc * 32 + quad * 8)] = afO[kc];
    }
  }
  int row0 = wv * 16 + quad * 4;
  float mkv[4];
#pragma unroll
  for (int r = 0; r < 4; r++) mkv[r] = mk[rb + row0 + r];
  stage_write_h(WlA, s0, tid);
  __syncthreads();   // B1: WlA(Wo0)
  WStageH s2;
  if (Wk) stage_load_h(s2, Wk, tid);
  floatx4 acc[4];
  gemm4_s(WlA, afO, lm, quad, acc);
  // epilogue half 0 (cols 0..63): f = O + relu(acc+b); z = Zin + f*mk
#pragma unroll
  for (int nt = 0; nt < 4; nt++) {
    int col = nt * 16 + lm;
    float bn = obias[col];
#pragma unroll
    for (int r = 0; r < 4; r++) {
      int row = row0 + r;
      size_t g = (size_t)(rb + row) * 128 + col;
      float ov = bf2f(Xl[swz(row, col)]);
      float f = ov + fmaxf(acc[nt][r] + bn, 0.f);
      float zv = Zin[g] + f * mkv[r];
      Zout[g] = zv;
      Xl[swz(row, col)] = f2bf(zv);
    }
  }
  stage_write_h(WlB, s1, tid);
  __syncthreads();   // B2: WlB(Wo1)
  WStageH s3;
  if (Wk) stage_load_h(s3, Wk + 8192, tid);
  gemm4_s(WlB, afO, lm, quad, acc);
  // epilogue half 1 (cols 64..127)
#pragma unroll
  for (int nt = 0; nt < 4; nt++) {
    int col = 64 + nt * 16 + lm;
    float bn = obias[col];
#pragma unroll
    for (int r = 0; r < 4; r++) {
      int row = row0 + r;
      size_t g = (size_t)(rb + row) * 128 + col;
      float ov = bf2f(Xl[swz(row, col)]);
      float f = ov + fmaxf(acc[nt][r] + bn, 0.f);
      float zv = Zin[g] + f * mkv[r];
      Zout[g] = zv;
      Xl[swz(row, col)] = f2bf(zv);
    }
  }
  if (Wk == nullptr) return;
  bf16x8 af[4];
  load_af_s(Xl, wv, lm, quad, af);   // af = new-Z fragments (wave-local)
  stage_write_h(WlA, s2, tid);
  __syncthreads();   // B3: WlA(Wk0)
  WStageH s4; stage_load_h(s4, Wv, tid);
  gemm4_s(WlA, af, lm, quad, acc);
  store_sl4(Xl, acc, kbias, wv, lm, quad, 0);
  stage_write_h(WlB, s3, tid);
  __syncthreads();   // B4: WlB(Wk1)
  WStageH s5; stage_load_h(s5, Wv + 8192, tid);
  gemm4_s(WlB, af, lm, quad, acc);
  store_sl4(Xl, acc, kbias, wv, lm, quad, 64);
  write_hs_s(Xl, Kb, rb, 12, tid);
  stage_write_h(WlA, s4, tid);
  __syncthreads();   // B5: WlA(Wv0)
  WStageH s6; stage_load_h(s6, Wq, tid);
  gemm4_s(WlA, af, lm, quad, acc);
  store_sl4(Xl, acc, vbias, wv, lm, quad, 0);
  stage_write_h(WlB, s5, tid);
  __syncthreads();   // B6: WlB(Wv1)
  WStageH s7; stage_load_h(s7, Wq + 8192, tid);
  gemm4_s(WlB, af, lm, quad, acc);
  store_sl4(Xl, acc, vbias, wv, lm, quad, 64);
  write_hs_s(Xl, Vb, rb, 12, tid);
  stage_write_h(WlA, s6, tid);
  __syncthreads();   // B7: WlA(Wq0)
  gemm4_s(WlA, af, lm, quad, acc);
  store_sl4(Xl, acc, qbias, wv, lm, quad, 0);
  stage_write_h(WlB, s7, tid);
  __syncthreads();   // B8: WlB(Wq1)
  gemm4_s(WlB, af, lm, quad, acc);
  store_sl4(Xl, acc, qbias, wv, lm, quad, 64);
  write_hs_s(Xl, Qb, rb, 12, tid);
}

// ---------------------------------------------------------------------------
extern "C" void kernel_launch(void* const* d_in, const int* in_sizes, int n_in,
                              void* d_out, int out_size, void* d_ws,
                              size_t ws_size, hipStream_t stream) {
  const float* cx    = (const float*)d_in[0];
  const float* value = (const float*)d_in[1];
  const float* mask  = (const float*)d_in[2];
  const float* iff_w = (const float*)d_in[4];
  const float* iff_b = (const float*)d_in[5];
  const float* indp  = (const float*)d_in[6];
  const float* q0w = (const float*)d_in[7];  const float* q0b = (const float*)d_in[8];
  const float* k0w = (const float*)d_in[9];  const float* k0b = (const float*)d_in[10];
  const float* v0w = (const float*)d_in[11]; const float* v0b = (const float*)d_in[12];
  const float* o0w = (const float*)d_in[13]; const float* o0b = (const float*)d_in[14];
  const float* q1w = (const float*)d_in[15]; const float* q1b = (const float*)d_in[16];
  const float* k1w = (const float*)d_in[17]; const float* k1b = (const float*)d_in[18];
  const float* v1w = (const float*)d_in[19]; const float* v1b = (const float*)d_in[20];
  const float* o1w = (const float*)d_in[21]; const float* o1b = (const float*)d_in[22];

  char* ws = (char*)d_ws;
  short* Wt    = (short*)ws;  ws += (size_t)24 * 16384 * 2;
  int*   order = (int*)ws;    ws += (size_t)NBATCH * OBS * 4;
  float* mk_g  = (float*)ws;  ws += (size_t)NBATCH * OBS * 4;
  float* Z     = (float*)ws;  ws += (size_t)NBATCH * OBS * DK * 4;
  short* Qb    = (short*)ws;  ws += (size_t)NBATCH * OBS * DK * 2;
  short* Kb    = (short*)ws;  ws += (size_t)NBATCH * OBS * DK * 2;
  short* Vb    = (short*)ws;  ws += (size_t)NBATCH * OBS * DK * 2;
  short* Ob    = (short*)ws;  ws += (size_t)NBATCH * OBS * DK * 2;
  short* qh_b  = (short*)ws;  ws += (size_t)3 * 128 * DK * 2;
  short* khb   = (short*)ws;  ws += (size_t)NBATCH * NH * 128 * DH * 2;
  short* vhb   = (short*)ws;  ws += (size_t)NBATCH * NH * 128 * DH * 2;
  float* Opart = (float*)ws;  ws += (size_t)8 * 64 * 128 * 32 * 4;
  float* mpart = (float*)ws;  ws += (size_t)8 * 64 * 128 * 4;
  float* lpart = (float*)ws;  ws += (size_t)8 * 64 * 128 * 4;

  float* outZ  = (float*)d_out;
  float* outMk = outZ + (size_t)NBATCH * OBS * DK;

  prep_build_kernel<<<40, 1024, 0, stream>>>(q0w, k0w, v0w, o0w, q1w, k1w,
                                             v1w, o1w, Wt, mask, order, mk_g,
                                             outMk);

  const short* W[3][8];
  for (int l = 0; l < 3; l++)
    for (int wi = 0; wi < 8; wi++) W[l][wi] = Wt + (size_t)(l * 8 + wi) * 16384;

  fusedA_kernel<<<1030, 256, 0, stream>>>(
      order, mk_g, cx, value, iff_w, iff_b, Z,
      W[0][1], k0b, Kb, W[0][2], v0b, Vb, W[0][4], q1b, Qb,
      indp, Wt, q0b, qh_b);

  for (int l = 0; l < 3; l++) {
    attn1_kernel<<<dim3(64, 8), 256, 0, stream>>>(
        qh_b + (size_t)l * 16384, Kb, Vb, mk_g, Opart, mpart, lpart);
    fusedB_kernel<<<32, 1024, 0, stream>>>(
        Opart, mpart, lpart, qh_b + (size_t)l * 16384,
        W[l][3], o0b + (size_t)l * 128,
        W[l][5], k1b + (size_t)l * 128,
        W[l][6], v1b + (size_t)l * 128, khb, vhb);
    attn2_kernel<<<dim3(64, 64), 256, 0, stream>>>(Qb, khb, vhb, Ob);
    if (l < 2) {
      fusedC_kernel<<<1024, 256, 0, stream>>>(
          Ob, W[l][7], o1b + (size_t)l * 128, mk_g, Z, Z,
          W[l + 1][1], k0b + (size_t)(l + 1) * 128, Kb,
          W[l + 1][2], v0b + (size_t)(l + 1) * 128, Vb,
          W[l + 1][4], q1b + (size_t)(l + 1) * 128, Qb);
    } else {
      fusedC_kernel<<<1024, 256, 0, stream>>>(
          Ob, W[l][7], o1b + (size_t)l * 128, mk_g, Z, outZ,
          nullptr, nullptr, nullptr, nullptr, nullptr, nullptr,
          nullptr, nullptr, nullptr);
    }
  }
}

// Round 11
// 458.254 us; speedup vs baseline: 1.2054x; 1.2054x over previous
//
#include <hip/hip_runtime.h>
#include <math.h>

#define NBATCH 16
#define SEQL   512
#define DIM    41
#define LDFLAT (SEQL*DIM)   // 20992
#define OBS    4096
#define DK     128
#define NH     4
#define DH     32

typedef short bf16x8 __attribute__((ext_vector_type(8)));
typedef short short8v __attribute__((ext_vector_type(8)));
typedef float floatx4 __attribute__((ext_vector_type(4)));

__device__ __forceinline__ short f2bf(float f) {
  union { float f; unsigned u; } v;
  v.f = f;
  unsigned r = (v.u + 0x7fffu + ((v.u >> 16) & 1u)) >> 16;
  return (short)r;
}
__device__ __forceinline__ float bf2f(short s) {
  union { unsigned u; float f; } v;
  v.u = ((unsigned)(unsigned short)s) << 16;
  return v.f;
}

// ---- R20 (FINAL): exact revert to R15, the session's verified best -------
// R15 = 458.2us: R13 structure (half-weight dbuf, 64-row blocks, 3/CU,
// zero write-amplification) + attn1 K/V register prefetch + Vtc stride 74.
// R19 post-mortem: depth-2 weight prefetch SPILLED the staged registers to
// scratch (FETCH 1.8->42MB, WRITE 84->182MB at unchanged VGPR_Count) ->
// 552us. Every later structural hypothesis (R14 128-row blocks, R16
// deferred stores / parallel KV, R17 attn2-4/CU + parallel scan, R18
// attn2+fusedC merge, R19 depth-2 prefetch) was null or regressive;
// the remaining gap to the ~150us traffic roofline is a latency plateau
// of this decomposition at source level. R15 stands.

__device__ __forceinline__ int swz(int row, int col) {  // col in shorts
  return row * 128 + ((((col >> 3) ^ row) & 15) << 3) + (col & 7);
}

// ---- 256-thread half-weight staging (16KB: 64 rows x 128 k) ----
typedef struct { int4 v[4]; } WStageH;
__device__ __forceinline__ void stage_load_h(WStageH& s,
                                             const short* __restrict__ Wh,
                                             int tid) {
#pragma unroll
  for (int k = 0; k < 4; k++)
    s.v[k] = *(const int4*)&Wh[(size_t)tid * 8 + (size_t)k * 2048];
}
__device__ __forceinline__ void stage_write_h(short* Wl, const WStageH& s,
                                              int tid) {
#pragma unroll
  for (int k = 0; k < 4; k++) {
    int i = tid * 8 + k * 2048;           // < 8192
    *(int4*)&Wl[swz(i >> 7, i & 127)] = s.v[k];
  }
}
// ---- 1024-thread full-weight staging (32KB) ----
typedef struct { int4 v[2]; } WStageF;
__device__ __forceinline__ void stage_load_f(WStageF& s,
                                             const short* __restrict__ W,
                                             int tid) {
#pragma unroll
  for (int k = 0; k < 2; k++)
    s.v[k] = *(const int4*)&W[(size_t)tid * 8 + (size_t)k * 8192];
}
__device__ __forceinline__ void stage_write_f(short* Wl, const WStageF& s,
                                              int tid) {
#pragma unroll
  for (int k = 0; k < 2; k++) {
    int i = tid * 8 + k * 8192;           // < 16384
    *(int4*)&Wl[swz(i >> 7, i & 127)] = s.v[k];
  }
}

// 4-nt GEMM against a 64-row weight buffer (one half)
__device__ __forceinline__ void gemm4_s(const short* Wl, const bf16x8 af[4],
                                        int lm, int quad, floatx4 acc[4]) {
#pragma unroll
  for (int nt = 0; nt < 4; nt++) acc[nt] = (floatx4){0.f, 0.f, 0.f, 0.f};
#pragma unroll
  for (int kc = 0; kc < 4; kc++) {
    bf16x8 a = af[kc];
#pragma unroll
    for (int nt = 0; nt < 4; nt++) {
      bf16x8 b = *(const bf16x8*)&Wl[swz(nt * 16 + lm, kc * 32 + quad * 8)];
      acc[nt] = __builtin_amdgcn_mfma_f32_16x16x32_bf16(a, b, acc[nt], 0, 0, 0);
    }
  }
}
// 2-nt GEMM against a full 128-row buffer, col-quarter colq
__device__ __forceinline__ void gemm2_s(const short* Wl, const bf16x8 af[4],
                                        int colq, int lm, int quad,
                                        floatx4 acc[2]) {
#pragma unroll
  for (int nt = 0; nt < 2; nt++) acc[nt] = (floatx4){0.f, 0.f, 0.f, 0.f};
#pragma unroll
  for (int kc = 0; kc < 4; kc++) {
    bf16x8 a = af[kc];
#pragma unroll
    for (int nt = 0; nt < 2; nt++) {
      bf16x8 b = *(const bf16x8*)&Wl[swz(colq * 32 + nt * 16 + lm,
                                         kc * 32 + quad * 8)];
      acc[nt] = __builtin_amdgcn_mfma_f32_16x16x32_bf16(a, b, acc[nt], 0, 0, 0);
    }
  }
}
__device__ __forceinline__ void load_af_s(const short* Xl, int strip, int lm,
                                          int quad, bf16x8 af[4]) {
#pragma unroll
  for (int kc = 0; kc < 4; kc++)
    af[kc] = *(const bf16x8*)&Xl[swz(strip * 16 + lm, kc * 32 + quad * 8)];
}
// stage bias-added bf16 half-result (wave-local rows), cols colbase..+63
__device__ __forceinline__ void store_sl4(short* Sl, const floatx4 acc[4],
                                          const float* __restrict__ bias,
                                          int wv, int lm, int quad,
                                          int colbase) {
#pragma unroll
  for (int nt = 0; nt < 4; nt++) {
    int col = colbase + nt * 16 + lm;
    float bn = bias[col];
#pragma unroll
    for (int r = 0; r < 4; r++)
      Sl[swz(wv * 16 + quad * 4 + r, col)] = f2bf(acc[nt][r] + bn);
  }
}
// write Sl rows rb..rb+63 to head-split out (wave-local rows: rr=tid>>2)
__device__ __forceinline__ void write_hs_s(const short* Sl,
                                           short* __restrict__ out, int rb,
                                           int nshift, int tid) {
  int rr = tid >> 2, hh = tid & 3;
  int r = rb + rr;
  int bb = r >> nshift, nn = r & ((1 << nshift) - 1);
  size_t o = (((size_t)(bb * NH + hh) << nshift) + nn) * 32;
#pragma unroll
  for (int j = 0; j < 4; j++)
    *(int4*)&out[o + j * 8] = *(int4*)&Sl[swz(rr, hh * 32 + j * 8)];
}
// 1024-thread quarter write: wave (strip,colq) writes its own 16 rows x head
__device__ __forceinline__ void write_hs_q(const short* Sl,
                                           short* __restrict__ out, int rb,
                                           int nshift, int strip, int colq,
                                           int lane) {
  int rr = strip * 16 + (lane >> 2);
  int r = rb + rr;
  int bb = r >> nshift, nn = r & ((1 << nshift) - 1);
  size_t o = (((size_t)(bb * NH + colq) << nshift) + nn) * 32 + (lane & 3) * 8;
  *(int4*)&out[o] = *(const int4*)&Sl[swz(rr, colq * 32 + (lane & 3) * 8)];
}

// ---------------------------------------------------------------------------
// Kernel: merged weight-prep (blocks 0..23) + stable-order scan (blocks 24..39)
// ---------------------------------------------------------------------------
__global__ __launch_bounds__(1024) void prep_build_kernel(
    const float* __restrict__ q0w, const float* __restrict__ k0w,
    const float* __restrict__ v0w, const float* __restrict__ o0w,
    const float* __restrict__ q1w, const float* __restrict__ k1w,
    const float* __restrict__ v1w, const float* __restrict__ o1w,
    short* __restrict__ Wt,
    const float* __restrict__ mask, int* __restrict__ order,
    float* __restrict__ mk_out, float* __restrict__ mk_out2) {
  __shared__ float Tl[128 * 132];
  __shared__ int wsums[16];
  __shared__ int s_total_ones;
  __shared__ int s_chunk_ones;
  __shared__ int s_ones_base;
  __shared__ int s_zeros_base;
  int tid = threadIdx.x;

  if (blockIdx.x < 24) {
    int id = blockIdx.x, l = id >> 3, wi = id & 7;
    const float* s;
    switch (wi) {
      case 0: s = q0w; break; case 1: s = k0w; break;
      case 2: s = v0w; break; case 3: s = o0w; break;
      case 4: s = q1w; break; case 5: s = k1w; break;
      case 6: s = v1w; break; default: s = o1w; break;
    }
    s += (size_t)l * 16384;
    for (int i = tid * 4; i < 16384; i += 4096) {
      int k = i >> 7, n = i & 127;
      float4 x = *(const float4*)&s[i];
      Tl[k * 132 + n + 0] = x.x; Tl[k * 132 + n + 1] = x.y;
      Tl[k * 132 + n + 2] = x.z; Tl[k * 132 + n + 3] = x.w;
    }
    __syncthreads();
    short* dst = Wt + (size_t)id * 16384;
    int n = tid >> 3, k0 = (tid & 7) * 16;
    for (int jc = 0; jc < 2; jc++) {
      short8v t;
#pragma unroll
      for (int j = 0; j < 8; j++) t[j] = f2bf(Tl[(k0 + jc * 8 + j) * 132 + n]);
      *(short8v*)&dst[n * 128 + k0 + jc * 8] = t;
    }
    return;
  }

  int b = blockIdx.x - 24;
  const float* m = mask + (size_t)b * LDFLAT;
  int lane = tid & 63, w = tid >> 6;

  int cnt = 0;
  for (int j = tid; j < LDFLAT; j += 1024) cnt += (m[j] > 0.f) ? 1 : 0;
  for (int off = 32; off > 0; off >>= 1) cnt += __shfl_xor(cnt, off);
  if (lane == 0) wsums[w] = cnt;
  __syncthreads();
  if (tid == 0) {
    int t = 0;
    for (int i = 0; i < 16; i++) t += wsums[i];
    s_total_ones = t; s_ones_base = 0; s_zeros_base = 0;
  }
  __syncthreads();
  int total_ones = s_total_ones;

  for (int c0 = 0; c0 < LDFLAT; c0 += 1024) {
    __syncthreads();
    int j = c0 + tid;
    bool valid = (j < LDFLAT);
    float mv = valid ? m[j] : 0.f;
    int one = (valid && mv > 0.f) ? 1 : 0;
    int v = one;
    for (int off = 1; off < 64; off <<= 1) {
      int t = __shfl_up(v, (unsigned)off);
      if (lane >= off) v += t;
    }
    if (lane == 63) wsums[w] = v;
    __syncthreads();
    if (tid == 0) {
      int run = 0;
      for (int i = 0; i < 16; i++) { int t = wsums[i]; wsums[i] = run; run += t; }
      s_chunk_ones = run;
    }
    __syncthreads();
    int ones_before = (v - one) + wsums[w];
    int ob = s_ones_base, zb = s_zeros_base, chunk_ones = s_chunk_ones;
    int rem = LDFLAT - c0;
    int chunk_valid = rem < 1024 ? rem : 1024;
    int valid_before = tid < rem ? tid : rem;
    if (valid) {
      int pos = one ? (ob + ones_before)
                    : (total_ones + zb + (valid_before - ones_before));
      if (pos < OBS) {
        order[b * OBS + pos] = j;
        mk_out[b * OBS + pos] = mv;
        mk_out2[b * OBS + pos] = mv;
      }
    }
    __syncthreads();
    if (tid == 0) {
      s_ones_base = ob + chunk_ones;
      s_zeros_base = zb + (chunk_valid - chunk_ones);
    }
  }
}

// ---------------------------------------------------------------------------
// Kernel: fusedA — embed (layer-0 Z) + K0/V0/Q1 projections (blocks 0..1023)
//                + ind-point Q projections for all 3 layers (blocks 1024..1029)
// R13 structure: half-weight dbuf, 48KB LDS -> 3 blocks/CU, 6 barriers.
// ---------------------------------------------------------------------------
__global__ __launch_bounds__(256, 3) void fusedA_kernel(
    const int* __restrict__ order, const float* __restrict__ mk_g,
    const float* __restrict__ cx, const float* __restrict__ value,
    const float* __restrict__ iff_w, const float* __restrict__ iff_b,
    float* __restrict__ Z,
    const short* __restrict__ Wk, const float* __restrict__ kbias,
    short* __restrict__ Kb,
    const short* __restrict__ Wv, const float* __restrict__ vbias,
    short* __restrict__ Vb,
    const short* __restrict__ Wq, const float* __restrict__ qbias,
    short* __restrict__ Qb,
    const float* __restrict__ indp, const short* __restrict__ WtAll,
    const float* __restrict__ q0b_all, short* __restrict__ qh_b) {
  __shared__ __align__(16) short Xl[64 * 128];
  __shared__ __align__(16) short WlA[64 * 128];
  __shared__ __align__(16) short WlB[64 * 128];
  int tid = threadIdx.x;
  int wv = tid >> 6, lane = tid & 63, lm = lane & 15, quad = lane >> 4;
  int r_l = lane >> 2, seg = lane & 3;
  int lrow = wv * 16 + r_l;      // wave-local row this lane helps fill

  if (blockIdx.x >= 1024) {
    // ---- qh_proj path: both halves staged upfront, 1 barrier ----
    int id = blockIdx.x - 1024;
    int l = id >> 1, rbq = (id & 1) * 64;
    const float* X = indp + (size_t)l * 16384 + (size_t)rbq * 128;
    const short* W = WtAll + (size_t)(l * 8) * 16384;  // q0w^T
    const float* bias = q0b_all + (size_t)l * 128;
    short* out = qh_b + (size_t)l * 16384;
    WStageH sA, sB;
    stage_load_h(sA, W, tid);
    stage_load_h(sB, W + 8192, tid);
    const float* Xr = X + (size_t)lrow * 128;
#pragma unroll
    for (int jj = 0; jj < 8; jj++) {
      int col = seg * 32 + jj * 4;
      float4 x = *(const float4*)&Xr[col];
      *(short4*)&Xl[swz(lrow, col)] =
          make_short4(f2bf(x.x), f2bf(x.y), f2bf(x.z), f2bf(x.w));
    }
    stage_write_h(WlA, sA, tid);
    stage_write_h(WlB, sB, tid);
    __syncthreads();
    bf16x8 af[4];
    load_af_s(Xl, wv, lm, quad, af);
    floatx4 acc[4];
    gemm4_s(WlA, af, lm, quad, acc);
    store_sl4(Xl, acc, bias, wv, lm, quad, 0);
    gemm4_s(WlB, af, lm, quad, acc);
    store_sl4(Xl, acc, bias, wv, lm, quad, 64);
    write_hs_s(Xl, out, rbq, 7, tid);
    return;
  }

  int rb = blockIdx.x * 64;
  WStageH s0; stage_load_h(s0, Wk, tid);     // Wk half0 (oldest in flight)
  int grow = rb + lrow;
  int bb = grow >> 12;
  int j = order[grow];               // 4 lanes/row share -> broadcast-coalesced
  int l = j / DIM, d = j - l * DIM;
  float t = cx[bb * SEQL + l];
  float u = value[(size_t)bb * LDFLAT + j];
  float mkv = mk_g[grow];
#pragma unroll
  for (int jj = 0; jj < 8; jj++) {
    int col = seg * 32 + jj * 4;
    float4 w0 = *(const float4*)&iff_w[d * DK + col];
    float4 w1 = *(const float4*)&iff_w[41 * DK + col];
    float4 w2 = *(const float4*)&iff_w[42 * DK + col];
    float4 b4 = *(const float4*)&iff_b[col];
    float4 z;
    z.x = fmaxf(w0.x + t * w1.x + u * w2.x + b4.x, 0.f) * mkv;
    z.y = fmaxf(w0.y + t * w1.y + u * w2.y + b4.y, 0.f) * mkv;
    z.z = fmaxf(w0.z + t * w1.z + u * w2.z + b4.z, 0.f) * mkv;
    z.w = fmaxf(w0.w + t * w1.w + u * w2.w + b4.w, 0.f) * mkv;
    *(float4*)&Z[(size_t)grow * DK + col] = z;
    *(short4*)&Xl[swz(lrow, col)] =
        make_short4(f2bf(z.x), f2bf(z.y), f2bf(z.z), f2bf(z.w));
  }
  stage_write_h(WlA, s0, tid);
  __syncthreads();   // B1: Xl(embed) + WlA(Wk0)
  WStageH s1; stage_load_h(s1, Wk + 8192, tid);
  bf16x8 af[4];
  load_af_s(Xl, wv, lm, quad, af);   // af cached for all GEMMs
  floatx4 acc[4];
  gemm4_s(WlA, af, lm, quad, acc);
  store_sl4(Xl, acc, kbias, wv, lm, quad, 0);
  stage_write_h(WlB, s1, tid);
  __syncthreads();   // B2: WlB(Wk1)
  WStageH s2; stage_load_h(s2, Wv, tid);
  gemm4_s(WlB, af, lm, quad, acc);
  store_sl4(Xl, acc, kbias, wv, lm, quad, 64);
  write_hs_s(Xl, Kb, rb, 12, tid);
  stage_write_h(WlA, s2, tid);
  __syncthreads();   // B3: WlA(Wv0)
  WStageH s3; stage_load_h(s3, Wv + 8192, tid);
  gemm4_s(WlA, af, lm, quad, acc);
  store_sl4(Xl, acc, vbias, wv, lm, quad, 0);
  stage_write_h(WlB, s3, tid);
  __syncthreads();   // B4: WlB(Wv1)
  WStageH s4; stage_load_h(s4, Wq, tid);
  gemm4_s(WlB, af, lm, quad, acc);
  store_sl4(Xl, acc, vbias, wv, lm, quad, 64);
  write_hs_s(Xl, Vb, rb, 12, tid);
  stage_write_h(WlA, s4, tid);
  __syncthreads();   // B5: WlA(Wq0)
  WStageH s5; stage_load_h(s5, Wq + 8192, tid);
  gemm4_s(WlA, af, lm, quad, acc);
  store_sl4(Xl, acc, qbias, wv, lm, quad, 0);
  stage_write_h(WlB, s5, tid);
  __syncthreads();   // B6: WlB(Wq1)
  gemm4_s(WlB, af, lm, quad, acc);
  store_sl4(Xl, acc, qbias, wv, lm, quad, 64);
  write_hs_s(Xl, Qb, rb, 12, tid);
}

// ---------------------------------------------------------------------------
// Kernel: MAB1 attention (bf16), flash over 8 key splits. grid (64, 8).
// R15: K/V chunk register prefetch; Vtc stride 74 (bank-conflict-free).
// ---------------------------------------------------------------------------
__global__ __launch_bounds__(256) void attn1_kernel(
    const short* __restrict__ Qh,   // (NH,128,32) bf16, layer base
    const short* __restrict__ Kh, const short* __restrict__ Vh,
    const float* __restrict__ mk,
    float* __restrict__ Opart, float* __restrict__ mpart,
    float* __restrict__ lpart) {
  __shared__ __align__(16) short Ql[128 * 40];
  __shared__ __align__(16) short Kc[64 * 40];
  __shared__ __align__(16) short Vtc[32 * 74];
  __shared__ __align__(16) short Pl[128 * 72];
  __shared__ float mkc[64];
  int bh = blockIdx.x;
  int b = bh >> 2, h = bh & 3;
  int ks = blockIdx.y;
  int tid = threadIdx.x;
  int wv = tid >> 6, lane = tid & 63, lm = lane & 15, quad = lane >> 4;

  const float scale = 0.08838834764831845f;
  const short* kbase = Kh + ((size_t)bh * OBS + ks * 512) * 32;
  const short* vbase = Vh + ((size_t)bh * OBS + ks * 512) * 32;
  const float* mkb = mk + (size_t)b * OBS + ks * 512;

  // prefetch chunk 0 K/V + mk into registers (overlaps Q staging)
  int i0 = tid * 8;
  int r0 = i0 >> 5, cv = i0 & 31;
  int4 kreg = *(const int4*)&kbase[i0];
  int4 vreg = *(const int4*)&vbase[i0];
  float mreg = (tid < 64) ? mkb[tid] : 0.f;

  const short* qbg = Qh + (size_t)h * 128 * 32;
  for (int i = tid * 8; i < 128 * 32; i += 2048) {
    int r = i >> 5, c = i & 31;
    *(int4*)&Ql[r * 40 + c] = *(const int4*)&qbg[i];
  }
  __syncthreads();
  bf16x8 aq[2];
  aq[0] = *(bf16x8*)&Ql[(wv * 32 + lm) * 40 + quad * 8];
  aq[1] = *(bf16x8*)&Ql[(wv * 32 + 16 + lm) * 40 + quad * 8];

  float m_i[2][4], l_i[2][4];
  floatx4 oacc[2][2];
#pragma unroll
  for (int mt = 0; mt < 2; mt++) {
#pragma unroll
    for (int r = 0; r < 4; r++) { m_i[mt][r] = -1e30f; l_i[mt][r] = 0.f; }
    oacc[mt][0] = (floatx4){0.f, 0.f, 0.f, 0.f};
    oacc[mt][1] = (floatx4){0.f, 0.f, 0.f, 0.f};
  }

  for (int ch = 0; ch < 8; ch++) {
    __syncthreads();   // prev chunk's Kc/Vtc reads done
    *(int4*)&Kc[r0 * 40 + cv] = kreg;
    {
      short* vv = (short*)&vreg;
#pragma unroll
      for (int j = 0; j < 8; j++) Vtc[(cv + j) * 74 + r0] = vv[j];
    }
    if (tid < 64) mkc[tid] = mreg;
    if (ch < 7) {      // issue next chunk's loads; latency hides under compute
      kreg = *(const int4*)&kbase[(ch + 1) * 2048 + i0];
      vreg = *(const int4*)&vbase[(ch + 1) * 2048 + i0];
      if (tid < 64) mreg = mkb[(ch + 1) * 64 + tid];
    }
    __syncthreads();   // Kc/Vtc/mkc ready

    floatx4 sf[2][4];
#pragma unroll
    for (int nt = 0; nt < 4; nt++) {
      bf16x8 bfrag = *(bf16x8*)&Kc[(nt * 16 + lm) * 40 + quad * 8];
      floatx4 z = {0.f, 0.f, 0.f, 0.f};
      sf[0][nt] = __builtin_amdgcn_mfma_f32_16x16x32_bf16(aq[0], bfrag, z, 0, 0, 0);
      sf[1][nt] = __builtin_amdgcn_mfma_f32_16x16x32_bf16(aq[1], bfrag, z, 0, 0, 0);
    }
#pragma unroll
    for (int nt = 0; nt < 4; nt++) {
      float mkv = mkc[nt * 16 + lm];
      bool ok = mkv > 0.f;
#pragma unroll
      for (int mt = 0; mt < 2; mt++)
#pragma unroll
        for (int r = 0; r < 4; r++)
          sf[mt][nt][r] = ok ? sf[mt][nt][r] * scale : -1e10f;
    }
#pragma unroll
    for (int mt = 0; mt < 2; mt++) {
#pragma unroll
      for (int r = 0; r < 4; r++) {
        float mx = fmaxf(fmaxf(sf[mt][0][r], sf[mt][1][r]),
                         fmaxf(sf[mt][2][r], sf[mt][3][r]));
        mx = fmaxf(mx, __shfl_xor(mx, 1));
        mx = fmaxf(mx, __shfl_xor(mx, 2));
        mx = fmaxf(mx, __shfl_xor(mx, 4));
        mx = fmaxf(mx, __shfl_xor(mx, 8));
        float mn = fmaxf(m_i[mt][r], mx);
        float al = __expf(m_i[mt][r] - mn);
        float ps = 0.f;
#pragma unroll
        for (int nt = 0; nt < 4; nt++) {
          float p = __expf(sf[mt][nt][r] - mn);
          sf[mt][nt][r] = p;
          ps += p;
        }
        ps += __shfl_xor(ps, 1);
        ps += __shfl_xor(ps, 2);
        ps += __shfl_xor(ps, 4);
        ps += __shfl_xor(ps, 8);
        l_i[mt][r] = l_i[mt][r] * al + ps;
        m_i[mt][r] = mn;
        oacc[mt][0] *= al;
        oacc[mt][1] *= al;
      }
    }
#pragma unroll
    for (int mt = 0; mt < 2; mt++)
#pragma unroll
      for (int nt = 0; nt < 4; nt++)
#pragma unroll
        for (int r = 0; r < 4; r++)
          Pl[(wv * 32 + mt * 16 + quad * 4 + r) * 72 + nt * 16 + lm] =
              f2bf(sf[mt][nt][r]);
#pragma unroll
    for (int kc = 0; kc < 2; kc++) {
      bf16x8 vf0 = *(bf16x8*)&Vtc[lm * 74 + kc * 32 + quad * 8];
      bf16x8 vf1 = *(bf16x8*)&Vtc[(16 + lm) * 74 + kc * 32 + quad * 8];
#pragma unroll
      for (int mt = 0; mt < 2; mt++) {
        bf16x8 pf = *(bf16x8*)&Pl[(wv * 32 + mt * 16 + lm) * 72 + kc * 32 + quad * 8];
        oacc[mt][0] = __builtin_amdgcn_mfma_f32_16x16x32_bf16(pf, vf0, oacc[mt][0], 0, 0, 0);
        oacc[mt][1] = __builtin_amdgcn_mfma_f32_16x16x32_bf16(pf, vf1, oacc[mt][1], 0, 0, 0);
      }
    }
  }
  float* ob = Opart + (size_t)(ks * 64 + bh) * 128 * 32;
#pragma unroll
  for (int mt = 0; mt < 2; mt++) {
#pragma unroll
    for (int r = 0; r < 4; r++) {
      int row = wv * 32 + mt * 16 + quad * 4 + r;
      ob[(size_t)row * 32 + lm] = oacc[mt][0][r];
      ob[(size_t)row * 32 + 16 + lm] = oacc[mt][1][r];
      if (lm == 0) {
        mpart[(size_t)(ks * 64 + bh) * 128 + row] = m_i[mt][r];
        lpart[(size_t)(ks * 64 + bh) * 128 + row] = l_i[mt][r];
      }
    }
  }
}

// ---------------------------------------------------------------------------
// Kernel: fusedB — attn1 combine + fc_o + K1/V1 projections. grid 32 x 1024.
// 16 waves (4 row-strips x 4 col-quarters); full-weight dbuf.
// ---------------------------------------------------------------------------
__global__ __launch_bounds__(1024) void fusedB_kernel(
    const float* __restrict__ Opart, const float* __restrict__ mpart,
    const float* __restrict__ lpart, const short* __restrict__ qh,
    const short* __restrict__ Wo, const float* __restrict__ obias,
    const short* __restrict__ Wk, const float* __restrict__ kbias,
    const short* __restrict__ Wv, const float* __restrict__ vbias,
    short* __restrict__ khb, short* __restrict__ vhb) {
  __shared__ __align__(16) short Xl[64 * 128];
  __shared__ __align__(16) short WlA[128 * 128];
  __shared__ __align__(16) short WlB[128 * 128];
  int tid = threadIdx.x;
  int rb = blockIdx.x * 64;           // row in 2048 = b*128 + n
  int b = rb >> 7, n0 = rb & 127;
  int wv = tid >> 6, lane = tid & 63, lm = lane & 15, quad = lane >> 4;
  int strip = wv & 3, colq = wv >> 2;
  WStageF sWo; stage_load_f(sWo, Wo, tid);
  // combine: 256 (row,head) pairs x 8 lanes = 2 passes of 1024
#pragma unroll
  for (int p = 0; p < 2; p++) {
    int slot = p * 1024 + tid;
    int pair = slot >> 3;
    int hh = pair & 3, rr = pair >> 2;
    int c4 = (slot & 7) * 4;
    int n = n0 + rr;
    int bh = b * 4 + hh;
    float mv[8], lv[8], m = -1e30f;
#pragma unroll
    for (int s = 0; s < 8; s++) {
      mv[s] = mpart[(size_t)(s * 64 + bh) * 128 + n];
      lv[s] = lpart[(size_t)(s * 64 + bh) * 128 + n];
      m = fmaxf(m, mv[s]);
    }
    float l = 0.f, oa0 = 0.f, oa1 = 0.f, oa2 = 0.f, oa3 = 0.f;
#pragma unroll
    for (int s = 0; s < 8; s++) {
      float w = __expf(mv[s] - m);
      l += lv[s] * w;
      float4 v = *(const float4*)&Opart[((size_t)(s * 64 + bh) * 128 + n) * 32 + c4];
      oa0 += v.x * w; oa1 += v.y * w; oa2 += v.z * w; oa3 += v.w * w;
    }
    float li = 1.f / l;
    int2 qi = *(const int2*)&qh[((size_t)hh * 128 + n) * 32 + c4];
    const short* qs = (const short*)&qi;
    short4 o4;
    o4.x = f2bf(bf2f(qs[0]) + oa0 * li);
    o4.y = f2bf(bf2f(qs[1]) + oa1 * li);
    o4.z = f2bf(bf2f(qs[2]) + oa2 * li);
    o4.w = f2bf(bf2f(qs[3]) + oa3 * li);
    *(short4*)&Xl[swz(rr, hh * 32 + c4)] = o4;
  }
  stage_write_f(WlA, sWo, tid);
  __syncthreads();   // B1: Xl(O) + WlA(Wo)
  bf16x8 afO[4];
  load_af_s(Xl, strip, lm, quad, afO);
  __syncthreads();   // B1b: all O reads done before H writes
  WStageF sWk; stage_load_f(sWk, Wk, tid);
  floatx4 acc[2];
  gemm2_s(WlA, afO, colq, lm, quad, acc);
  // H = O + relu(acc + bias): in-place on this wave's (strip,colq) quarter
#pragma unroll
  for (int nt = 0; nt < 2; nt++) {
    int col = colq * 32 + nt * 16 + lm;
    float bn = obias[col];
#pragma unroll
    for (int r = 0; r < 4; r++) {
      int row = strip * 16 + quad * 4 + r;
      float ov = bf2f(Xl[swz(row, col)]);
      Xl[swz(row, col)] = f2bf(ov + fmaxf(acc[nt][r] + bn, 0.f));
    }
  }
  stage_write_f(WlB, sWk, tid);
  __syncthreads();   // B2: Xl(H) complete + WlB(Wk)
  bf16x8 afH[4];
  load_af_s(Xl, strip, lm, quad, afH);
  __syncthreads();   // B2b: all H reads done before K-result writes
  WStageF sWv; stage_load_f(sWv, Wv, tid);
  gemm2_s(WlB, afH, colq, lm, quad, acc);
#pragma unroll
  for (int nt = 0; nt < 2; nt++) {
    int col = colq * 32 + nt * 16 + lm;
    float bn = kbias[col];
#pragma unroll
    for (int r = 0; r < 4; r++)
      Xl[swz(strip * 16 + quad * 4 + r, col)] = f2bf(acc[nt][r] + bn);
  }
  write_hs_q(Xl, khb, rb, 7, strip, colq, lane);   // wave-local quarter
  stage_write_f(WlA, sWv, tid);
  __syncthreads();   // B3: WlA(Wv); all khb reads done before V writes
  gemm2_s(WlA, afH, colq, lm, quad, acc);
#pragma unroll
  for (int nt = 0; nt < 2; nt++) {
    int col = colq * 32 + nt * 16 + lm;
    float bn = vbias[col];
#pragma unroll
    for (int r = 0; r < 4; r++)
      Xl[swz(strip * 16 + quad * 4 + r, col)] = f2bf(acc[nt][r] + bn);
  }
  write_hs_q(Xl, vhb, rb, 7, strip, colq, lane);
}

// ---------------------------------------------------------------------------
// Kernel: MAB2 attention, register softmax. grid (64, 64). LDS ~42 KB.
// ---------------------------------------------------------------------------
__global__ __launch_bounds__(256) void attn2_kernel(
    const short* __restrict__ Qh, const short* __restrict__ Kh,
    const short* __restrict__ Vh, short* __restrict__ O) {
  __shared__ __align__(16) short Kl[128 * 40];
  __shared__ __align__(16) short Vt[32 * 136];
  __shared__ __align__(16) short Ql[64 * 40];
  __shared__ __align__(16) short Pl[64 * 136];
  int bh = blockIdx.x;
  int b = bh >> 2, h = bh & 3;
  int q0 = blockIdx.y * 64;
  int tid = threadIdx.x;
  int wv = tid >> 6, lane = tid & 63, lm = lane & 15, quad = lane >> 4;
  const short* kb = Kh + (size_t)bh * 128 * 32;
  const short* vb = Vh + (size_t)bh * 128 * 32;
  const short* qb = Qh + ((size_t)bh * OBS + q0) * 32;

  for (int i = tid * 8; i < 128 * 32; i += 2048) {
    int r = i >> 5, c = i & 31;
    *(int4*)&Kl[r * 40 + c] = *(const int4*)&kb[i];
  }
  for (int i = tid * 8; i < 64 * 32; i += 2048) {
    int r = i >> 5, c = i & 31;
    *(int4*)&Ql[r * 40 + c] = *(const int4*)&qb[i];
  }
  for (int i = tid * 8; i < 128 * 32; i += 2048) {
    int r = i >> 5, c = i & 31;
    int4 vv4 = *(const int4*)&vb[i];
    short* vv = (short*)&vv4;
#pragma unroll
    for (int j = 0; j < 8; j++) Vt[(c + j) * 136 + r] = vv[j];
  }
  __syncthreads();

  const float scale = 0.08838834764831845f;
  bf16x8 afrag = *(bf16x8*)&Ql[(wv * 16 + lm) * 40 + quad * 8];
  floatx4 sf[8];
#pragma unroll
  for (int nt = 0; nt < 8; nt++) {
    bf16x8 bfrag = *(bf16x8*)&Kl[(nt * 16 + lm) * 40 + quad * 8];
    floatx4 z = {0.f, 0.f, 0.f, 0.f};
    sf[nt] = __builtin_amdgcn_mfma_f32_16x16x32_bf16(afrag, bfrag, z, 0, 0, 0);
  }
#pragma unroll
  for (int nt = 0; nt < 8; nt++) sf[nt] *= scale;
  float linv[4];
#pragma unroll
  for (int r = 0; r < 4; r++) {
    float mx = sf[0][r];
#pragma unroll
    for (int nt = 1; nt < 8; nt++) mx = fmaxf(mx, sf[nt][r]);
    mx = fmaxf(mx, __shfl_xor(mx, 1));
    mx = fmaxf(mx, __shfl_xor(mx, 2));
    mx = fmaxf(mx, __shfl_xor(mx, 4));
    mx = fmaxf(mx, __shfl_xor(mx, 8));
    float sum = 0.f;
#pragma unroll
    for (int nt = 0; nt < 8; nt++) {
      float p = __expf(sf[nt][r] - mx);
      sf[nt][r] = p;
      sum += p;
    }
    sum += __shfl_xor(sum, 1);
    sum += __shfl_xor(sum, 2);
    sum += __shfl_xor(sum, 4);
    sum += __shfl_xor(sum, 8);
    linv[r] = 1.f / sum;
  }
#pragma unroll
  for (int nt = 0; nt < 8; nt++)
#pragma unroll
    for (int r = 0; r < 4; r++)
      Pl[(wv * 16 + quad * 4 + r) * 136 + nt * 16 + lm] = f2bf(sf[nt][r]);

  floatx4 oacc[2] = {{0.f, 0.f, 0.f, 0.f}, {0.f, 0.f, 0.f, 0.f}};
#pragma unroll
  for (int kc = 0; kc < 4; kc++) {
    bf16x8 pf = *(bf16x8*)&Pl[(wv * 16 + lm) * 136 + kc * 32 + quad * 8];
#pragma unroll
    for (int nt2 = 0; nt2 < 2; nt2++) {
      bf16x8 vf = *(bf16x8*)&Vt[(nt2 * 16 + lm) * 136 + kc * 32 + quad * 8];
      oacc[nt2] = __builtin_amdgcn_mfma_f32_16x16x32_bf16(pf, vf, oacc[nt2], 0, 0, 0);
    }
  }
  // stage O+Q residual in Pl rows (wave-local), then coalesced int4 store
  short* Ol = Pl;
#pragma unroll
  for (int nt2 = 0; nt2 < 2; nt2++) {
#pragma unroll
    for (int r = 0; r < 4; r++) {
      int qrow = wv * 16 + quad * 4 + r;
      float q = bf2f(Ql[qrow * 40 + nt2 * 16 + lm]);
      Ol[qrow * 136 + nt2 * 16 + lm] = f2bf(q + oacc[nt2][r] * linv[r]);
    }
  }
  int rr = tid >> 2, seg = tid & 3;      // wave-local Ol rows
  size_t o = ((size_t)b * OBS + q0 + rr) * 128 + h * 32 + seg * 8;
  *(int4*)&O[o] = *(int4*)&Ol[rr * 136 + seg * 8];
}

// ---------------------------------------------------------------------------
// Kernel: fusedC — fc_o + residual Z update + next layer's K0/V0/Q1.
// grid 1024 (64 rows). Wk==null => last layer (no projections).
// R13 structure: half-weight dbuf, 48KB LDS -> 3 blocks/CU, 8 barriers.
// ---------------------------------------------------------------------------
__global__ __launch_bounds__(256, 3) void fusedC_kernel(
    const short* __restrict__ Ob, const short* __restrict__ Wo,
    const float* __restrict__ obias, const float* __restrict__ mk,
    const float* __restrict__ Zin, float* __restrict__ Zout,
    const short* __restrict__ Wk, const float* __restrict__ kbias,
    short* __restrict__ Kb,
    const short* __restrict__ Wv, const float* __restrict__ vbias,
    short* __restrict__ Vb,
    const short* __restrict__ Wq, const float* __restrict__ qbias,
    short* __restrict__ Qb) {
  __shared__ __align__(16) short Xl[64 * 128];
  __shared__ __align__(16) short WlA[64 * 128];
  __shared__ __align__(16) short WlB[64 * 128];
  int tid = threadIdx.x;
  int rb = blockIdx.x * 64;
  int wv = tid >> 6, lane = tid & 63, lm = lane & 15, quad = lane >> 4;

  WStageH s0; stage_load_h(s0, Wo, tid);
  bf16x8 afO[4];
  {
    const short* arow = Ob + (size_t)(rb + wv * 16 + lm) * 128;
#pragma unroll
    for (int kc = 0; kc < 4; kc++) {
      afO[kc] = *(const bf16x8*)&arow[kc * 32 + quad * 8];
      *(bf16x8*)&Xl[swz(wv * 16 + lm, kc * 32 + quad * 8)] = afO[kc];
    }
  }
  int row0 = wv * 16 + quad * 4;
  float mkv[4];
#pragma unroll
  for (int r = 0; r < 4; r++) mkv[r] = mk[rb + row0 + r];
  stage_write_h(WlA, s0, tid);
  __syncthreads();   // B1: WlA(Wo0)
  WStageH s1; stage_load_h(s1, Wo + 8192, tid);
  floatx4 acc[4];
  gemm4_s(WlA, afO, lm, quad, acc);
  // epilogue half 0 (cols 0..63): f = O + relu(acc+b); z = Zin + f*mk
#pragma unroll
  for (int nt = 0; nt < 4; nt++) {
    int col = nt * 16 + lm;
    float bn = obias[col];
#pragma unroll
    for (int r = 0; r < 4; r++) {
      int row = row0 + r;
      size_t g = (size_t)(rb + row) * 128 + col;
      float ov = bf2f(Xl[swz(row, col)]);
      float f = ov + fmaxf(acc[nt][r] + bn, 0.f);
      float zv = Zin[g] + f * mkv[r];
      Zout[g] = zv;
      Xl[swz(row, col)] = f2bf(zv);
    }
  }
  stage_write_h(WlB, s1, tid);
  __syncthreads();   // B2: WlB(Wo1)
  WStageH s2;
  if (Wk) stage_load_h(s2, Wk, tid);
  gemm4_s(WlB, afO, lm, quad, acc);
  // epilogue half 1 (cols 64..127)
#pragma unroll
  for (int nt = 0; nt < 4; nt++) {
    int col = 64 + nt * 16 + lm;
    float bn = obias[col];
#pragma unroll
    for (int r = 0; r < 4; r++) {
      int row = row0 + r;
      size_t g = (size_t)(rb + row) * 128 + col;
      float ov = bf2f(Xl[swz(row, col)]);
      float f = ov + fmaxf(acc[nt][r] + bn, 0.f);
      float zv = Zin[g] + f * mkv[r];
      Zout[g] = zv;
      Xl[swz(row, col)] = f2bf(zv);
    }
  }
  if (Wk == nullptr) return;
  bf16x8 af[4];
  load_af_s(Xl, wv, lm, quad, af);   // af = new-Z fragments (wave-local)
  stage_write_h(WlA, s2, tid);
  __syncthreads();   // B3: WlA(Wk0)
  WStageH s3; stage_load_h(s3, Wk + 8192, tid);
  gemm4_s(WlA, af, lm, quad, acc);
  store_sl4(Xl, acc, kbias, wv, lm, quad, 0);
  stage_write_h(WlB, s3, tid);
  __syncthreads();   // B4: WlB(Wk1)
  WStageH s4; stage_load_h(s4, Wv, tid);
  gemm4_s(WlB, af, lm, quad, acc);
  store_sl4(Xl, acc, kbias, wv, lm, quad, 64);
  write_hs_s(Xl, Kb, rb, 12, tid);
  stage_write_h(WlA, s4, tid);
  __syncthreads();   // B5: WlA(Wv0)
  WStageH s5; stage_load_h(s5, Wv + 8192, tid);
  gemm4_s(WlA, af, lm, quad, acc);
  store_sl4(Xl, acc, vbias, wv, lm, quad, 0);
  stage_write_h(WlB, s5, tid);
  __syncthreads();   // B6: WlB(Wv1)
  WStageH s6; stage_load_h(s6, Wq, tid);
  gemm4_s(WlB, af, lm, quad, acc);
  store_sl4(Xl, acc, vbias, wv, lm, quad, 64);
  write_hs_s(Xl, Vb, rb, 12, tid);
  stage_write_h(WlA, s6, tid);
  __syncthreads();   // B7: WlA(Wq0)
  WStageH s7; stage_load_h(s7, Wq + 8192, tid);
  gemm4_s(WlA, af, lm, quad, acc);
  store_sl4(Xl, acc, qbias, wv, lm, quad, 0);
  stage_write_h(WlB, s7, tid);
  __syncthreads();   // B8: WlB(Wq1)
  gemm4_s(WlB, af, lm, quad, acc);
  store_sl4(Xl, acc, qbias, wv, lm, quad, 64);
  write_hs_s(Xl, Qb, rb, 12, tid);
}

// ---------------------------------------------------------------------------
extern "C" void kernel_launch(void* const* d_in, const int* in_sizes, int n_in,
                              void* d_out, int out_size, void* d_ws,
                              size_t ws_size, hipStream_t stream) {
  const float* cx    = (const float*)d_in[0];
  const float* value = (const float*)d_in[1];
  const float* mask  = (const float*)d_in[2];
  const float* iff_w = (const float*)d_in[4];
  const float* iff_b = (const float*)d_in[5];
  const float* indp  = (const float*)d_in[6];
  const float* q0w = (const float*)d_in[7];  const float* q0b = (const float*)d_in[8];
  const float* k0w = (const float*)d_in[9];  const float* k0b = (const float*)d_in[10];
  const float* v0w = (const float*)d_in[11]; const float* v0b = (const float*)d_in[12];
  const float* o0w = (const float*)d_in[13]; const float* o0b = (const float*)d_in[14];
  const float* q1w = (const float*)d_in[15]; const float* q1b = (const float*)d_in[16];
  const float* k1w = (const float*)d_in[17]; const float* k1b = (const float*)d_in[18];
  const float* v1w = (const float*)d_in[19]; const float* v1b = (const float*)d_in[20];
  const float* o1w = (const float*)d_in[21]; const float* o1b = (const float*)d_in[22];

  char* ws = (char*)d_ws;
  short* Wt    = (short*)ws;  ws += (size_t)24 * 16384 * 2;
  int*   order = (int*)ws;    ws += (size_t)NBATCH * OBS * 4;
  float* mk_g  = (float*)ws;  ws += (size_t)NBATCH * OBS * 4;
  float* Z     = (float*)ws;  ws += (size_t)NBATCH * OBS * DK * 4;
  short* Qb    = (short*)ws;  ws += (size_t)NBATCH * OBS * DK * 2;
  short* Kb    = (short*)ws;  ws += (size_t)NBATCH * OBS * DK * 2;
  short* Vb    = (short*)ws;  ws += (size_t)NBATCH * OBS * DK * 2;
  short* Ob    = (short*)ws;  ws += (size_t)NBATCH * OBS * DK * 2;
  short* qh_b  = (short*)ws;  ws += (size_t)3 * 128 * DK * 2;
  short* khb   = (short*)ws;  ws += (size_t)NBATCH * NH * 128 * DH * 2;
  short* vhb   = (short*)ws;  ws += (size_t)NBATCH * NH * 128 * DH * 2;
  float* Opart = (float*)ws;  ws += (size_t)8 * 64 * 128 * 32 * 4;
  float* mpart = (float*)ws;  ws += (size_t)8 * 64 * 128 * 4;
  float* lpart = (float*)ws;  ws += (size_t)8 * 64 * 128 * 4;

  float* outZ  = (float*)d_out;
  float* outMk = outZ + (size_t)NBATCH * OBS * DK;

  prep_build_kernel<<<40, 1024, 0, stream>>>(q0w, k0w, v0w, o0w, q1w, k1w,
                                             v1w, o1w, Wt, mask, order, mk_g,
                                             outMk);

  const short* W[3][8];
  for (int l = 0; l < 3; l++)
    for (int wi = 0; wi < 8; wi++) W[l][wi] = Wt + (size_t)(l * 8 + wi) * 16384;

  fusedA_kernel<<<1030, 256, 0, stream>>>(
      order, mk_g, cx, value, iff_w, iff_b, Z,
      W[0][1], k0b, Kb, W[0][2], v0b, Vb, W[0][4], q1b, Qb,
      indp, Wt, q0b, qh_b);

  for (int l = 0; l < 3; l++) {
    attn1_kernel<<<dim3(64, 8), 256, 0, stream>>>(
        qh_b + (size_t)l * 16384, Kb, Vb, mk_g, Opart, mpart, lpart);
    fusedB_kernel<<<32, 1024, 0, stream>>>(
        Opart, mpart, lpart, qh_b + (size_t)l * 16384,
        W[l][3], o0b + (size_t)l * 128,
        W[l][5], k1b + (size_t)l * 128,
        W[l][6], v1b + (size_t)l * 128, khb, vhb);
    attn2_kernel<<<dim3(64, 64), 256, 0, stream>>>(Qb, khb, vhb, Ob);
    if (l < 2) {
      fusedC_kernel<<<1024, 256, 0, stream>>>(
          Ob, W[l][7], o1b + (size_t)l * 128, mk_g, Z, Z,
          W[l + 1][1], k0b + (size_t)(l + 1) * 128, Kb,
          W[l + 1][2], v0b + (size_t)(l + 1) * 128, Vb,
          W[l + 1][4], q1b + (size_t)(l + 1) * 128, Qb);
    } else {
      fusedC_kernel<<<1024, 256, 0, stream>>>(
          Ob, W[l][7], o1b + (size_t)l * 128, mk_g, Z, outZ,
          nullptr, nullptr, nullptr, nullptr, nullptr, nullptr,
          nullptr, nullptr, nullptr);
    }
  }
}

// Round 12
// 446.495 us; speedup vs baseline: 1.2372x; 1.0263x over previous
//
#include <hip/hip_runtime.h>
#include <math.h>

#define NBATCH 16
#define SEQL   512
#define DIM    41
#define LDFLAT (SEQL*DIM)   // 20992
#define OBS    4096
#define DK     128
#define NH     4
#define DH     32

typedef short bf16x8 __attribute__((ext_vector_type(8)));
typedef short short8v __attribute__((ext_vector_type(8)));
typedef float floatx4 __attribute__((ext_vector_type(4)));

__device__ __forceinline__ short f2bf(float f) {
  union { float f; unsigned u; } v;
  v.f = f;
  unsigned r = (v.u + 0x7fffu + ((v.u >> 16) & 1u)) >> 16;
  return (short)r;
}
__device__ __forceinline__ float bf2f(short s) {
  union { unsigned u; float f; } v;
  v.u = ((unsigned)(unsigned short)s) << 16;
  return v.f;
}

// ---- R21: R15 base + direct-to-LDS weight staging (global_load_lds) -------
// R20 confirmed R15 anchor (458.25us, counters match). Not at roofline
// (HBM 22%, Mfma 5%). Last untried first-class lever: global_load_lds
// (guide Common-mistake #1 — compiler never auto-emits). Old staging:
// global->VGPR->(vmcnt wait)->ds_write x4 per phase. New: width-16 glds
// lands weights directly in LDS; barrier's vmcnt(0) drain is the only sync;
// frees ~16 staged VGPRs (R19's spill mode impossible — pressure goes DOWN).
// Requirements handled:
//  (1) glds writes LINEARLY (wave-uniform base + lane*16) => the XOR swizzle
//      moves to the PRODUCER: prep writes Wt PRE-SWIZZLED (dst[swz(n,c)];
//      8-short segments stay contiguous => short8v store unchanged). All
//      weight consumers converted; LDS reads keep swz() unchanged.
//  (2) issue-after-free: glds writes dest as loads complete, so each glds
//      issues right after the barrier retiring all reads of that buffer
//      (fusedC Wk0 issue moved post-B1 -> post-B2). Full GEMM phase of
//      cover per load; barrier counts unchanged (A:6, B:5, C:8).

__device__ __forceinline__ int swz(int row, int col) {  // col in shorts
  return row * 128 + ((((col >> 3) ^ row) & 15) << 3) + (col & 7);
}

// ---- direct global->LDS 16B copy (wave-uniform LDS base + lane*16) ----
__device__ __forceinline__ void glds16(const short* g, short* l) {
  __builtin_amdgcn_global_load_lds(
      (const __attribute__((address_space(1))) void*)g,
      (__attribute__((address_space(3))) void*)l, 16, 0, 0);
}
// 256-thread half-weight (16KB: 8192 shorts), Wt pre-swizzled => linear dest
__device__ __forceinline__ void stage_glds_h(short* Wl,
                                             const short* __restrict__ W,
                                             int tid) {
  int wb = (tid >> 6) * 512;   // wave-uniform LDS base (shorts)
#pragma unroll
  for (int k = 0; k < 4; k++)
    glds16(&W[(size_t)tid * 8 + (size_t)k * 2048], &Wl[wb + k * 2048]);
}
// 1024-thread full-weight (32KB: 16384 shorts)
__device__ __forceinline__ void stage_glds_f(short* Wl,
                                             const short* __restrict__ W,
                                             int tid) {
  int wb = (tid >> 6) * 512;
#pragma unroll
  for (int k = 0; k < 2; k++)
    glds16(&W[(size_t)tid * 8 + (size_t)k * 8192], &Wl[wb + k * 8192]);
}

// 4-nt GEMM against a 64-row weight buffer (one half)
__device__ __forceinline__ void gemm4_s(const short* Wl, const bf16x8 af[4],
                                        int lm, int quad, floatx4 acc[4]) {
#pragma unroll
  for (int nt = 0; nt < 4; nt++) acc[nt] = (floatx4){0.f, 0.f, 0.f, 0.f};
#pragma unroll
  for (int kc = 0; kc < 4; kc++) {
    bf16x8 a = af[kc];
#pragma unroll
    for (int nt = 0; nt < 4; nt++) {
      bf16x8 b = *(const bf16x8*)&Wl[swz(nt * 16 + lm, kc * 32 + quad * 8)];
      acc[nt] = __builtin_amdgcn_mfma_f32_16x16x32_bf16(a, b, acc[nt], 0, 0, 0);
    }
  }
}
// 2-nt GEMM against a full 128-row buffer, col-quarter colq
__device__ __forceinline__ void gemm2_s(const short* Wl, const bf16x8 af[4],
                                        int colq, int lm, int quad,
                                        floatx4 acc[2]) {
#pragma unroll
  for (int nt = 0; nt < 2; nt++) acc[nt] = (floatx4){0.f, 0.f, 0.f, 0.f};
#pragma unroll
  for (int kc = 0; kc < 4; kc++) {
    bf16x8 a = af[kc];
#pragma unroll
    for (int nt = 0; nt < 2; nt++) {
      bf16x8 b = *(const bf16x8*)&Wl[swz(colq * 32 + nt * 16 + lm,
                                         kc * 32 + quad * 8)];
      acc[nt] = __builtin_amdgcn_mfma_f32_16x16x32_bf16(a, b, acc[nt], 0, 0, 0);
    }
  }
}
__device__ __forceinline__ void load_af_s(const short* Xl, int strip, int lm,
                                          int quad, bf16x8 af[4]) {
#pragma unroll
  for (int kc = 0; kc < 4; kc++)
    af[kc] = *(const bf16x8*)&Xl[swz(strip * 16 + lm, kc * 32 + quad * 8)];
}
// stage bias-added bf16 half-result (wave-local rows), cols colbase..+63
__device__ __forceinline__ void store_sl4(short* Sl, const floatx4 acc[4],
                                          const float* __restrict__ bias,
                                          int wv, int lm, int quad,
                                          int colbase) {
#pragma unroll
  for (int nt = 0; nt < 4; nt++) {
    int col = colbase + nt * 16 + lm;
    float bn = bias[col];
#pragma unroll
    for (int r = 0; r < 4; r++)
      Sl[swz(wv * 16 + quad * 4 + r, col)] = f2bf(acc[nt][r] + bn);
  }
}
// write Sl rows rb..rb+63 to head-split out (wave-local rows: rr=tid>>2)
__device__ __forceinline__ void write_hs_s(const short* Sl,
                                           short* __restrict__ out, int rb,
                                           int nshift, int tid) {
  int rr = tid >> 2, hh = tid & 3;
  int r = rb + rr;
  int bb = r >> nshift, nn = r & ((1 << nshift) - 1);
  size_t o = (((size_t)(bb * NH + hh) << nshift) + nn) * 32;
#pragma unroll
  for (int j = 0; j < 4; j++)
    *(int4*)&out[o + j * 8] = *(int4*)&Sl[swz(rr, hh * 32 + j * 8)];
}
// 1024-thread quarter write: wave (strip,colq) writes its own 16 rows x head
__device__ __forceinline__ void write_hs_q(const short* Sl,
                                           short* __restrict__ out, int rb,
                                           int nshift, int strip, int colq,
                                           int lane) {
  int rr = strip * 16 + (lane >> 2);
  int r = rb + rr;
  int bb = r >> nshift, nn = r & ((1 << nshift) - 1);
  size_t o = (((size_t)(bb * NH + colq) << nshift) + nn) * 32 + (lane & 3) * 8;
  *(int4*)&out[o] = *(const int4*)&Sl[swz(rr, colq * 32 + (lane & 3) * 8)];
}

// ---------------------------------------------------------------------------
// Kernel: merged weight-prep (blocks 0..23) + stable-order scan (blocks 24..39)
// R21: Wt written PRE-SWIZZLED so linear glds staging yields the swz layout.
// ---------------------------------------------------------------------------
__global__ __launch_bounds__(1024) void prep_build_kernel(
    const float* __restrict__ q0w, const float* __restrict__ k0w,
    const float* __restrict__ v0w, const float* __restrict__ o0w,
    const float* __restrict__ q1w, const float* __restrict__ k1w,
    const float* __restrict__ v1w, const float* __restrict__ o1w,
    short* __restrict__ Wt,
    const float* __restrict__ mask, int* __restrict__ order,
    float* __restrict__ mk_out, float* __restrict__ mk_out2) {
  __shared__ float Tl[128 * 132];
  __shared__ int wsums[16];
  __shared__ int s_total_ones;
  __shared__ int s_chunk_ones;
  __shared__ int s_ones_base;
  __shared__ int s_zeros_base;
  int tid = threadIdx.x;

  if (blockIdx.x < 24) {
    int id = blockIdx.x, l = id >> 3, wi = id & 7;
    const float* s;
    switch (wi) {
      case 0: s = q0w; break; case 1: s = k0w; break;
      case 2: s = v0w; break; case 3: s = o0w; break;
      case 4: s = q1w; break; case 5: s = k1w; break;
      case 6: s = v1w; break; default: s = o1w; break;
    }
    s += (size_t)l * 16384;
    for (int i = tid * 4; i < 16384; i += 4096) {
      int k = i >> 7, n = i & 127;
      float4 x = *(const float4*)&s[i];
      Tl[k * 132 + n + 0] = x.x; Tl[k * 132 + n + 1] = x.y;
      Tl[k * 132 + n + 2] = x.z; Tl[k * 132 + n + 3] = x.w;
    }
    __syncthreads();
    short* dst = Wt + (size_t)id * 16384;
    int n = tid >> 3, k0 = (tid & 7) * 16;
    for (int jc = 0; jc < 2; jc++) {
      short8v t;
#pragma unroll
      for (int j = 0; j < 8; j++) t[j] = f2bf(Tl[(k0 + jc * 8 + j) * 132 + n]);
      // pre-swizzled: segment-aligned cols stay contiguous (16B store OK)
      *(short8v*)&dst[swz(n, k0 + jc * 8)] = t;
    }
    return;
  }

  int b = blockIdx.x - 24;
  const float* m = mask + (size_t)b * LDFLAT;
  int lane = tid & 63, w = tid >> 6;

  int cnt = 0;
  for (int j = tid; j < LDFLAT; j += 1024) cnt += (m[j] > 0.f) ? 1 : 0;
  for (int off = 32; off > 0; off >>= 1) cnt += __shfl_xor(cnt, off);
  if (lane == 0) wsums[w] = cnt;
  __syncthreads();
  if (tid == 0) {
    int t = 0;
    for (int i = 0; i < 16; i++) t += wsums[i];
    s_total_ones = t; s_ones_base = 0; s_zeros_base = 0;
  }
  __syncthreads();
  int total_ones = s_total_ones;

  for (int c0 = 0; c0 < LDFLAT; c0 += 1024) {
    __syncthreads();
    int j = c0 + tid;
    bool valid = (j < LDFLAT);
    float mv = valid ? m[j] : 0.f;
    int one = (valid && mv > 0.f) ? 1 : 0;
    int v = one;
    for (int off = 1; off < 64; off <<= 1) {
      int t = __shfl_up(v, (unsigned)off);
      if (lane >= off) v += t;
    }
    if (lane == 63) wsums[w] = v;
    __syncthreads();
    if (tid == 0) {
      int run = 0;
      for (int i = 0; i < 16; i++) { int t = wsums[i]; wsums[i] = run; run += t; }
      s_chunk_ones = run;
    }
    __syncthreads();
    int ones_before = (v - one) + wsums[w];
    int ob = s_ones_base, zb = s_zeros_base, chunk_ones = s_chunk_ones;
    int rem = LDFLAT - c0;
    int chunk_valid = rem < 1024 ? rem : 1024;
    int valid_before = tid < rem ? tid : rem;
    if (valid) {
      int pos = one ? (ob + ones_before)
                    : (total_ones + zb + (valid_before - ones_before));
      if (pos < OBS) {
        order[b * OBS + pos] = j;
        mk_out[b * OBS + pos] = mv;
        mk_out2[b * OBS + pos] = mv;
      }
    }
    __syncthreads();
    if (tid == 0) {
      s_ones_base = ob + chunk_ones;
      s_zeros_base = zb + (chunk_valid - chunk_ones);
    }
  }
}

// ---------------------------------------------------------------------------
// Kernel: fusedA — embed (layer-0 Z) + K0/V0/Q1 projections (blocks 0..1023)
//                + ind-point Q projections for all 3 layers (blocks 1024..1029)
// R21: glds staging; each glds issued right after the barrier freeing its
// dest buffer; 6 barriers unchanged.
// ---------------------------------------------------------------------------
__global__ __launch_bounds__(256, 3) void fusedA_kernel(
    const int* __restrict__ order, const float* __restrict__ mk_g,
    const float* __restrict__ cx, const float* __restrict__ value,
    const float* __restrict__ iff_w, const float* __restrict__ iff_b,
    float* __restrict__ Z,
    const short* __restrict__ Wk, const float* __restrict__ kbias,
    short* __restrict__ Kb,
    const short* __restrict__ Wv, const float* __restrict__ vbias,
    short* __restrict__ Vb,
    const short* __restrict__ Wq, const float* __restrict__ qbias,
    short* __restrict__ Qb,
    const float* __restrict__ indp, const short* __restrict__ WtAll,
    const float* __restrict__ q0b_all, short* __restrict__ qh_b) {
  __shared__ __align__(16) short Xl[64 * 128];
  __shared__ __align__(16) short WlA[64 * 128];
  __shared__ __align__(16) short WlB[64 * 128];
  int tid = threadIdx.x;
  int wv = tid >> 6, lane = tid & 63, lm = lane & 15, quad = lane >> 4;
  int r_l = lane >> 2, seg = lane & 3;
  int lrow = wv * 16 + r_l;      // wave-local row this lane helps fill

  if (blockIdx.x >= 1024) {
    // ---- qh_proj path: both halves glds'd upfront, 1 barrier ----
    int id = blockIdx.x - 1024;
    int l = id >> 1, rbq = (id & 1) * 64;
    const float* X = indp + (size_t)l * 16384 + (size_t)rbq * 128;
    const short* W = WtAll + (size_t)(l * 8) * 16384;  // q0w^T (pre-swz)
    const float* bias = q0b_all + (size_t)l * 128;
    short* out = qh_b + (size_t)l * 16384;
    stage_glds_h(WlA, W, tid);
    stage_glds_h(WlB, W + 8192, tid);
    const float* Xr = X + (size_t)lrow * 128;
#pragma unroll
    for (int jj = 0; jj < 8; jj++) {
      int col = seg * 32 + jj * 4;
      float4 x = *(const float4*)&Xr[col];
      *(short4*)&Xl[swz(lrow, col)] =
          make_short4(f2bf(x.x), f2bf(x.y), f2bf(x.z), f2bf(x.w));
    }
    __syncthreads();   // drains glds (vmcnt) + Xl writes
    bf16x8 af[4];
    load_af_s(Xl, wv, lm, quad, af);
    floatx4 acc[4];
    gemm4_s(WlA, af, lm, quad, acc);
    store_sl4(Xl, acc, bias, wv, lm, quad, 0);
    gemm4_s(WlB, af, lm, quad, acc);
    store_sl4(Xl, acc, bias, wv, lm, quad, 64);
    write_hs_s(Xl, out, rbq, 7, tid);
    return;
  }

  int rb = blockIdx.x * 64;
  stage_glds_h(WlA, Wk, tid);        // Wk0 -> WlA (dest fresh)
  int grow = rb + lrow;
  int bb = grow >> 12;
  int j = order[grow];               // 4 lanes/row share -> broadcast-coalesced
  int l = j / DIM, d = j - l * DIM;
  float t = cx[bb * SEQL + l];
  float u = value[(size_t)bb * LDFLAT + j];
  float mkv = mk_g[grow];
#pragma unroll
  for (int jj = 0; jj < 8; jj++) {
    int col = seg * 32 + jj * 4;
    float4 w0 = *(const float4*)&iff_w[d * DK + col];
    float4 w1 = *(const float4*)&iff_w[41 * DK + col];
    float4 w2 = *(const float4*)&iff_w[42 * DK + col];
    float4 b4 = *(const float4*)&iff_b[col];
    float4 z;
    z.x = fmaxf(w0.x + t * w1.x + u * w2.x + b4.x, 0.f) * mkv;
    z.y = fmaxf(w0.y + t * w1.y + u * w2.y + b4.y, 0.f) * mkv;
    z.z = fmaxf(w0.z + t * w1.z + u * w2.z + b4.z, 0.f) * mkv;
    z.w = fmaxf(w0.w + t * w1.w + u * w2.w + b4.w, 0.f) * mkv;
    *(float4*)&Z[(size_t)grow * DK + col] = z;
    *(short4*)&Xl[swz(lrow, col)] =
        make_short4(f2bf(z.x), f2bf(z.y), f2bf(z.z), f2bf(z.w));
  }
  __syncthreads();   // B1: Xl(embed) + WlA(Wk0) landed
  stage_glds_h(WlB, Wk + 8192, tid);   // Wk1 -> WlB (dest fresh)
  bf16x8 af[4];
  load_af_s(Xl, wv, lm, quad, af);   // af cached for all GEMMs
  floatx4 acc[4];
  gemm4_s(WlA, af, lm, quad, acc);
  store_sl4(Xl, acc, kbias, wv, lm, quad, 0);
  __syncthreads();   // B2: WlB(Wk1) landed; WlA reads done
  stage_glds_h(WlA, Wv, tid);          // Wv0 -> WlA (freed at B2)
  gemm4_s(WlB, af, lm, quad, acc);
  store_sl4(Xl, acc, kbias, wv, lm, quad, 64);
  write_hs_s(Xl, Kb, rb, 12, tid);
  __syncthreads();   // B3: WlA(Wv0) landed; WlB reads done
  stage_glds_h(WlB, Wv + 8192, tid);   // Wv1 -> WlB (freed at B3)
  gemm4_s(WlA, af, lm, quad, acc);
  store_sl4(Xl, acc, vbias, wv, lm, quad, 0);
  __syncthreads();   // B4: WlB(Wv1) landed
  stage_glds_h(WlA, Wq, tid);          // Wq0 -> WlA (freed at B4)
  gemm4_s(WlB, af, lm, quad, acc);
  store_sl4(Xl, acc, vbias, wv, lm, quad, 64);
  write_hs_s(Xl, Vb, rb, 12, tid);
  __syncthreads();   // B5: WlA(Wq0) landed
  stage_glds_h(WlB, Wq + 8192, tid);   // Wq1 -> WlB (freed at B5)
  gemm4_s(WlA, af, lm, quad, acc);
  store_sl4(Xl, acc, qbias, wv, lm, quad, 0);
  __syncthreads();   // B6: WlB(Wq1) landed
  gemm4_s(WlB, af, lm, quad, acc);
  store_sl4(Xl, acc, qbias, wv, lm, quad, 64);
  write_hs_s(Xl, Qb, rb, 12, tid);
}

// ---------------------------------------------------------------------------
// Kernel: MAB1 attention (bf16), flash over 8 key splits. grid (64, 8).
// R15: K/V chunk register prefetch; Vtc stride 74 (bank-conflict-free).
// ---------------------------------------------------------------------------
__global__ __launch_bounds__(256) void attn1_kernel(
    const short* __restrict__ Qh,   // (NH,128,32) bf16, layer base
    const short* __restrict__ Kh, const short* __restrict__ Vh,
    const float* __restrict__ mk,
    float* __restrict__ Opart, float* __restrict__ mpart,
    float* __restrict__ lpart) {
  __shared__ __align__(16) short Ql[128 * 40];
  __shared__ __align__(16) short Kc[64 * 40];
  __shared__ __align__(16) short Vtc[32 * 74];
  __shared__ __align__(16) short Pl[128 * 72];
  __shared__ float mkc[64];
  int bh = blockIdx.x;
  int b = bh >> 2, h = bh & 3;
  int ks = blockIdx.y;
  int tid = threadIdx.x;
  int wv = tid >> 6, lane = tid & 63, lm = lane & 15, quad = lane >> 4;

  const float scale = 0.08838834764831845f;
  const short* kbase = Kh + ((size_t)bh * OBS + ks * 512) * 32;
  const short* vbase = Vh + ((size_t)bh * OBS + ks * 512) * 32;
  const float* mkb = mk + (size_t)b * OBS + ks * 512;

  // prefetch chunk 0 K/V + mk into registers (overlaps Q staging)
  int i0 = tid * 8;
  int r0 = i0 >> 5, cv = i0 & 31;
  int4 kreg = *(const int4*)&kbase[i0];
  int4 vreg = *(const int4*)&vbase[i0];
  float mreg = (tid < 64) ? mkb[tid] : 0.f;

  const short* qbg = Qh + (size_t)h * 128 * 32;
  for (int i = tid * 8; i < 128 * 32; i += 2048) {
    int r = i >> 5, c = i & 31;
    *(int4*)&Ql[r * 40 + c] = *(const int4*)&qbg[i];
  }
  __syncthreads();
  bf16x8 aq[2];
  aq[0] = *(bf16x8*)&Ql[(wv * 32 + lm) * 40 + quad * 8];
  aq[1] = *(bf16x8*)&Ql[(wv * 32 + 16 + lm) * 40 + quad * 8];

  float m_i[2][4], l_i[2][4];
  floatx4 oacc[2][2];
#pragma unroll
  for (int mt = 0; mt < 2; mt++) {
#pragma unroll
    for (int r = 0; r < 4; r++) { m_i[mt][r] = -1e30f; l_i[mt][r] = 0.f; }
    oacc[mt][0] = (floatx4){0.f, 0.f, 0.f, 0.f};
    oacc[mt][1] = (floatx4){0.f, 0.f, 0.f, 0.f};
  }

  for (int ch = 0; ch < 8; ch++) {
    __syncthreads();   // prev chunk's Kc/Vtc reads done
    *(int4*)&Kc[r0 * 40 + cv] = kreg;
    {
      short* vv = (short*)&vreg;
#pragma unroll
      for (int j = 0; j < 8; j++) Vtc[(cv + j) * 74 + r0] = vv[j];
    }
    if (tid < 64) mkc[tid] = mreg;
    if (ch < 7) {      // issue next chunk's loads; latency hides under compute
      kreg = *(const int4*)&kbase[(ch + 1) * 2048 + i0];
      vreg = *(const int4*)&vbase[(ch + 1) * 2048 + i0];
      if (tid < 64) mreg = mkb[(ch + 1) * 64 + tid];
    }
    __syncthreads();   // Kc/Vtc/mkc ready

    floatx4 sf[2][4];
#pragma unroll
    for (int nt = 0; nt < 4; nt++) {
      bf16x8 bfrag = *(bf16x8*)&Kc[(nt * 16 + lm) * 40 + quad * 8];
      floatx4 z = {0.f, 0.f, 0.f, 0.f};
      sf[0][nt] = __builtin_amdgcn_mfma_f32_16x16x32_bf16(aq[0], bfrag, z, 0, 0, 0);
      sf[1][nt] = __builtin_amdgcn_mfma_f32_16x16x32_bf16(aq[1], bfrag, z, 0, 0, 0);
    }
#pragma unroll
    for (int nt = 0; nt < 4; nt++) {
      float mkv = mkc[nt * 16 + lm];
      bool ok = mkv > 0.f;
#pragma unroll
      for (int mt = 0; mt < 2; mt++)
#pragma unroll
        for (int r = 0; r < 4; r++)
          sf[mt][nt][r] = ok ? sf[mt][nt][r] * scale : -1e10f;
    }
#pragma unroll
    for (int mt = 0; mt < 2; mt++) {
#pragma unroll
      for (int r = 0; r < 4; r++) {
        float mx = fmaxf(fmaxf(sf[mt][0][r], sf[mt][1][r]),
                         fmaxf(sf[mt][2][r], sf[mt][3][r]));
        mx = fmaxf(mx, __shfl_xor(mx, 1));
        mx = fmaxf(mx, __shfl_xor(mx, 2));
        mx = fmaxf(mx, __shfl_xor(mx, 4));
        mx = fmaxf(mx, __shfl_xor(mx, 8));
        float mn = fmaxf(m_i[mt][r], mx);
        float al = __expf(m_i[mt][r] - mn);
        float ps = 0.f;
#pragma unroll
        for (int nt = 0; nt < 4; nt++) {
          float p = __expf(sf[mt][nt][r] - mn);
          sf[mt][nt][r] = p;
          ps += p;
        }
        ps += __shfl_xor(ps, 1);
        ps += __shfl_xor(ps, 2);
        ps += __shfl_xor(ps, 4);
        ps += __shfl_xor(ps, 8);
        l_i[mt][r] = l_i[mt][r] * al + ps;
        m_i[mt][r] = mn;
        oacc[mt][0] *= al;
        oacc[mt][1] *= al;
      }
    }
#pragma unroll
    for (int mt = 0; mt < 2; mt++)
#pragma unroll
      for (int nt = 0; nt < 4; nt++)
#pragma unroll
        for (int r = 0; r < 4; r++)
          Pl[(wv * 32 + mt * 16 + quad * 4 + r) * 72 + nt * 16 + lm] =
              f2bf(sf[mt][nt][r]);
#pragma unroll
    for (int kc = 0; kc < 2; kc++) {
      bf16x8 vf0 = *(bf16x8*)&Vtc[lm * 74 + kc * 32 + quad * 8];
      bf16x8 vf1 = *(bf16x8*)&Vtc[(16 + lm) * 74 + kc * 32 + quad * 8];
#pragma unroll
      for (int mt = 0; mt < 2; mt++) {
        bf16x8 pf = *(bf16x8*)&Pl[(wv * 32 + mt * 16 + lm) * 72 + kc * 32 + quad * 8];
        oacc[mt][0] = __builtin_amdgcn_mfma_f32_16x16x32_bf16(pf, vf0, oacc[mt][0], 0, 0, 0);
        oacc[mt][1] = __builtin_amdgcn_mfma_f32_16x16x32_bf16(pf, vf1, oacc[mt][1], 0, 0, 0);
      }
    }
  }
  float* ob = Opart + (size_t)(ks * 64 + bh) * 128 * 32;
#pragma unroll
  for (int mt = 0; mt < 2; mt++) {
#pragma unroll
    for (int r = 0; r < 4; r++) {
      int row = wv * 32 + mt * 16 + quad * 4 + r;
      ob[(size_t)row * 32 + lm] = oacc[mt][0][r];
      ob[(size_t)row * 32 + 16 + lm] = oacc[mt][1][r];
      if (lm == 0) {
        mpart[(size_t)(ks * 64 + bh) * 128 + row] = m_i[mt][r];
        lpart[(size_t)(ks * 64 + bh) * 128 + row] = l_i[mt][r];
      }
    }
  }
}

// ---------------------------------------------------------------------------
// Kernel: fusedB — attn1 combine + fc_o + K1/V1 projections. grid 32 x 1024.
// R21: glds staging (dest freed before each issue); 5 barriers unchanged.
// ---------------------------------------------------------------------------
__global__ __launch_bounds__(1024) void fusedB_kernel(
    const float* __restrict__ Opart, const float* __restrict__ mpart,
    const float* __restrict__ lpart, const short* __restrict__ qh,
    const short* __restrict__ Wo, const float* __restrict__ obias,
    const short* __restrict__ Wk, const float* __restrict__ kbias,
    const short* __restrict__ Wv, const float* __restrict__ vbias,
    short* __restrict__ khb, short* __restrict__ vhb) {
  __shared__ __align__(16) short Xl[64 * 128];
  __shared__ __align__(16) short WlA[128 * 128];
  __shared__ __align__(16) short WlB[128 * 128];
  int tid = threadIdx.x;
  int rb = blockIdx.x * 64;           // row in 2048 = b*128 + n
  int b = rb >> 7, n0 = rb & 127;
  int wv = tid >> 6, lane = tid & 63, lm = lane & 15, quad = lane >> 4;
  int strip = wv & 3, colq = wv >> 2;
  stage_glds_f(WlA, Wo, tid);         // Wo -> WlA (dest fresh)
  // combine: 256 (row,head) pairs x 8 lanes = 2 passes of 1024
#pragma unroll
  for (int p = 0; p < 2; p++) {
    int slot = p * 1024 + tid;
    int pair = slot >> 3;
    int hh = pair & 3, rr = pair >> 2;
    int c4 = (slot & 7) * 4;
    int n = n0 + rr;
    int bh = b * 4 + hh;
    float mv[8], lv[8], m = -1e30f;
#pragma unroll
    for (int s = 0; s < 8; s++) {
      mv[s] = mpart[(size_t)(s * 64 + bh) * 128 + n];
      lv[s] = lpart[(size_t)(s * 64 + bh) * 128 + n];
      m = fmaxf(m, mv[s]);
    }
    float l = 0.f, oa0 = 0.f, oa1 = 0.f, oa2 = 0.f, oa3 = 0.f;
#pragma unroll
    for (int s = 0; s < 8; s++) {
      float w = __expf(mv[s] - m);
      l += lv[s] * w;
      float4 v = *(const float4*)&Opart[((size_t)(s * 64 + bh) * 128 + n) * 32 + c4];
      oa0 += v.x * w; oa1 += v.y * w; oa2 += v.z * w; oa3 += v.w * w;
    }
    float li = 1.f / l;
    int2 qi = *(const int2*)&qh[((size_t)hh * 128 + n) * 32 + c4];
    const short* qs = (const short*)&qi;
    short4 o4;
    o4.x = f2bf(bf2f(qs[0]) + oa0 * li);
    o4.y = f2bf(bf2f(qs[1]) + oa1 * li);
    o4.z = f2bf(bf2f(qs[2]) + oa2 * li);
    o4.w = f2bf(bf2f(qs[3]) + oa3 * li);
    *(short4*)&Xl[swz(rr, hh * 32 + c4)] = o4;
  }
  __syncthreads();   // B1: Xl(O) + WlA(Wo) landed
  bf16x8 afO[4];
  load_af_s(Xl, strip, lm, quad, afO);
  __syncthreads();   // B1b: all O reads done before H writes
  stage_glds_f(WlB, Wk, tid);         // Wk -> WlB (dest fresh)
  floatx4 acc[2];
  gemm2_s(WlA, afO, colq, lm, quad, acc);
  // H = O + relu(acc + bias): in-place on this wave's (strip,colq) quarter
#pragma unroll
  for (int nt = 0; nt < 2; nt++) {
    int col = colq * 32 + nt * 16 + lm;
    float bn = obias[col];
#pragma unroll
    for (int r = 0; r < 4; r++) {
      int row = strip * 16 + quad * 4 + r;
      float ov = bf2f(Xl[swz(row, col)]);
      Xl[swz(row, col)] = f2bf(ov + fmaxf(acc[nt][r] + bn, 0.f));
    }
  }
  __syncthreads();   // B2: Xl(H) complete + WlB(Wk) landed; WlA reads done
  bf16x8 afH[4];
  load_af_s(Xl, strip, lm, quad, afH);
  __syncthreads();   // B2b: all H reads done before K-result writes
  stage_glds_f(WlA, Wv, tid);         // Wv -> WlA (freed at B2)
  gemm2_s(WlB, afH, colq, lm, quad, acc);
#pragma unroll
  for (int nt = 0; nt < 2; nt++) {
    int col = colq * 32 + nt * 16 + lm;
    float bn = kbias[col];
#pragma unroll
    for (int r = 0; r < 4; r++)
      Xl[swz(strip * 16 + quad * 4 + r, col)] = f2bf(acc[nt][r] + bn);
  }
  write_hs_q(Xl, khb, rb, 7, strip, colq, lane);   // wave-local quarter
  __syncthreads();   // B3: WlA(Wv) landed; all khb reads done before V writes
  gemm2_s(WlA, afH, colq, lm, quad, acc);
#pragma unroll
  for (int nt = 0; nt < 2; nt++) {
    int col = colq * 32 + nt * 16 + lm;
    float bn = vbias[col];
#pragma unroll
    for (int r = 0; r < 4; r++)
      Xl[swz(strip * 16 + quad * 4 + r, col)] = f2bf(acc[nt][r] + bn);
  }
  write_hs_q(Xl, vhb, rb, 7, strip, colq, lane);
}

// ---------------------------------------------------------------------------
// Kernel: MAB2 attention, register softmax. grid (64, 64). LDS ~42 KB.
// ---------------------------------------------------------------------------
__global__ __launch_bounds__(256) void attn2_kernel(
    const short* __restrict__ Qh, const short* __restrict__ Kh,
    const short* __restrict__ Vh, short* __restrict__ O) {
  __shared__ __align__(16) short Kl[128 * 40];
  __shared__ __align__(16) short Vt[32 * 136];
  __shared__ __align__(16) short Ql[64 * 40];
  __shared__ __align__(16) short Pl[64 * 136];
  int bh = blockIdx.x;
  int b = bh >> 2, h = bh & 3;
  int q0 = blockIdx.y * 64;
  int tid = threadIdx.x;
  int wv = tid >> 6, lane = tid & 63, lm = lane & 15, quad = lane >> 4;
  const short* kb = Kh + (size_t)bh * 128 * 32;
  const short* vb = Vh + (size_t)bh * 128 * 32;
  const short* qb = Qh + ((size_t)bh * OBS + q0) * 32;

  for (int i = tid * 8; i < 128 * 32; i += 2048) {
    int r = i >> 5, c = i & 31;
    *(int4*)&Kl[r * 40 + c] = *(const int4*)&kb[i];
  }
  for (int i = tid * 8; i < 64 * 32; i += 2048) {
    int r = i >> 5, c = i & 31;
    *(int4*)&Ql[r * 40 + c] = *(const int4*)&qb[i];
  }
  for (int i = tid * 8; i < 128 * 32; i += 2048) {
    int r = i >> 5, c = i & 31;
    int4 vv4 = *(const int4*)&vb[i];
    short* vv = (short*)&vv4;
#pragma unroll
    for (int j = 0; j < 8; j++) Vt[(c + j) * 136 + r] = vv[j];
  }
  __syncthreads();

  const float scale = 0.08838834764831845f;
  bf16x8 afrag = *(bf16x8*)&Ql[(wv * 16 + lm) * 40 + quad * 8];
  floatx4 sf[8];
#pragma unroll
  for (int nt = 0; nt < 8; nt++) {
    bf16x8 bfrag = *(bf16x8*)&Kl[(nt * 16 + lm) * 40 + quad * 8];
    floatx4 z = {0.f, 0.f, 0.f, 0.f};
    sf[nt] = __builtin_amdgcn_mfma_f32_16x16x32_bf16(afrag, bfrag, z, 0, 0, 0);
  }
#pragma unroll
  for (int nt = 0; nt < 8; nt++) sf[nt] *= scale;
  float linv[4];
#pragma unroll
  for (int r = 0; r < 4; r++) {
    float mx = sf[0][r];
#pragma unroll
    for (int nt = 1; nt < 8; nt++) mx = fmaxf(mx, sf[nt][r]);
    mx = fmaxf(mx, __shfl_xor(mx, 1));
    mx = fmaxf(mx, __shfl_xor(mx, 2));
    mx = fmaxf(mx, __shfl_xor(mx, 4));
    mx = fmaxf(mx, __shfl_xor(mx, 8));
    float sum = 0.f;
#pragma unroll
    for (int nt = 0; nt < 8; nt++) {
      float p = __expf(sf[nt][r] - mx);
      sf[nt][r] = p;
      sum += p;
    }
    sum += __shfl_xor(sum, 1);
    sum += __shfl_xor(sum, 2);
    sum += __shfl_xor(sum, 4);
    sum += __shfl_xor(sum, 8);
    linv[r] = 1.f / sum;
  }
#pragma unroll
  for (int nt = 0; nt < 8; nt++)
#pragma unroll
    for (int r = 0; r < 4; r++)
      Pl[(wv * 16 + quad * 4 + r) * 136 + nt * 16 + lm] = f2bf(sf[nt][r]);

  floatx4 oacc[2] = {{0.f, 0.f, 0.f, 0.f}, {0.f, 0.f, 0.f, 0.f}};
#pragma unroll
  for (int kc = 0; kc < 4; kc++) {
    bf16x8 pf = *(bf16x8*)&Pl[(wv * 16 + lm) * 136 + kc * 32 + quad * 8];
#pragma unroll
    for (int nt2 = 0; nt2 < 2; nt2++) {
      bf16x8 vf = *(bf16x8*)&Vt[(nt2 * 16 + lm) * 136 + kc * 32 + quad * 8];
      oacc[nt2] = __builtin_amdgcn_mfma_f32_16x16x32_bf16(pf, vf, oacc[nt2], 0, 0, 0);
    }
  }
  // stage O+Q residual in Pl rows (wave-local), then coalesced int4 store
  short* Ol = Pl;
#pragma unroll
  for (int nt2 = 0; nt2 < 2; nt2++) {
#pragma unroll
    for (int r = 0; r < 4; r++) {
      int qrow = wv * 16 + quad * 4 + r;
      float q = bf2f(Ql[qrow * 40 + nt2 * 16 + lm]);
      Ol[qrow * 136 + nt2 * 16 + lm] = f2bf(q + oacc[nt2][r] * linv[r]);
    }
  }
  int rr = tid >> 2, seg = tid & 3;      // wave-local Ol rows
  size_t o = ((size_t)b * OBS + q0 + rr) * 128 + h * 32 + seg * 8;
  *(int4*)&O[o] = *(int4*)&Ol[rr * 136 + seg * 8];
}

// ---------------------------------------------------------------------------
// Kernel: fusedC — fc_o + residual Z update + next layer's K0/V0/Q1.
// grid 1024 (64 rows). Wk==null => last layer (no projections).
// R21: glds staging; each glds issued after the barrier freeing its dest
// (Wk0 moved post-B1 -> post-B2); 8 barriers unchanged.
// ---------------------------------------------------------------------------
__global__ __launch_bounds__(256, 3) void fusedC_kernel(
    const short* __restrict__ Ob, const short* __restrict__ Wo,
    const float* __restrict__ obias, const float* __restrict__ mk,
    const float* __restrict__ Zin, float* __restrict__ Zout,
    const short* __restrict__ Wk, const float* __restrict__ kbias,
    short* __restrict__ Kb,
    const short* __restrict__ Wv, const float* __restrict__ vbias,
    short* __restrict__ Vb,
    const short* __restrict__ Wq, const float* __restrict__ qbias,
    short* __restrict__ Qb) {
  __shared__ __align__(16) short Xl[64 * 128];
  __shared__ __align__(16) short WlA[64 * 128];
  __shared__ __align__(16) short WlB[64 * 128];
  int tid = threadIdx.x;
  int rb = blockIdx.x * 64;
  int wv = tid >> 6, lane = tid & 63, lm = lane & 15, quad = lane >> 4;

  stage_glds_h(WlA, Wo, tid);          // Wo0 -> WlA (dest fresh)
  bf16x8 afO[4];
  {
    const short* arow = Ob + (size_t)(rb + wv * 16 + lm) * 128;
#pragma unroll
    for (int kc = 0; kc < 4; kc++) {
      afO[kc] = *(const bf16x8*)&arow[kc * 32 + quad * 8];
      *(bf16x8*)&Xl[swz(wv * 16 + lm, kc * 32 + quad * 8)] = afO[kc];
    }
  }
  int row0 = wv * 16 + quad * 4;
  float mkv[4];
#pragma unroll
  for (int r = 0; r < 4; r++) mkv[r] = mk[rb + row0 + r];
  __syncthreads();   // B1: WlA(Wo0) landed + Xl(O) ready
  stage_glds_h(WlB, Wo + 8192, tid);   // Wo1 -> WlB (dest fresh)
  floatx4 acc[4];
  gemm4_s(WlA, afO, lm, quad, acc);
  // epilogue half 0 (cols 0..63): f = O + relu(acc+b); z = Zin + f*mk
#pragma unroll
  for (int nt = 0; nt < 4; nt++) {
    int col = nt * 16 + lm;
    float bn = obias[col];
#pragma unroll
    for (int r = 0; r < 4; r++) {
      int row = row0 + r;
      size_t g = (size_t)(rb + row) * 128 + col;
      float ov = bf2f(Xl[swz(row, col)]);
      float f = ov + fmaxf(acc[nt][r] + bn, 0.f);
      float zv = Zin[g] + f * mkv[r];
      Zout[g] = zv;
      Xl[swz(row, col)] = f2bf(zv);
    }
  }
  __syncthreads();   // B2: WlB(Wo1) landed; WlA reads done
  if (Wk) stage_glds_h(WlA, Wk, tid);  // Wk0 -> WlA (freed at B2)
  gemm4_s(WlB, afO, lm, quad, acc);
  // epilogue half 1 (cols 64..127)
#pragma unroll
  for (int nt = 0; nt < 4; nt++) {
    int col = 64 + nt * 16 + lm;
    float bn = obias[col];
#pragma unroll
    for (int r = 0; r < 4; r++) {
      int row = row0 + r;
      size_t g = (size_t)(rb + row) * 128 + col;
      float ov = bf2f(Xl[swz(row, col)]);
      float f = ov + fmaxf(acc[nt][r] + bn, 0.f);
      float zv = Zin[g] + f * mkv[r];
      Zout[g] = zv;
      Xl[swz(row, col)] = f2bf(zv);
    }
  }
  if (Wk == nullptr) return;
  bf16x8 af[4];
  load_af_s(Xl, wv, lm, quad, af);   // af = new-Z fragments (wave-local)
  __syncthreads();   // B3: WlA(Wk0) landed; WlB reads done
  stage_glds_h(WlB, Wk + 8192, tid);   // Wk1 -> WlB (freed at B3)
  gemm4_s(WlA, af, lm, quad, acc);
  store_sl4(Xl, acc, kbias, wv, lm, quad, 0);
  __syncthreads();   // B4: WlB(Wk1) landed; WlA reads done
  stage_glds_h(WlA, Wv, tid);          // Wv0 -> WlA
  gemm4_s(WlB, af, lm, quad, acc);
  store_sl4(Xl, acc, kbias, wv, lm, quad, 64);
  write_hs_s(Xl, Kb, rb, 12, tid);
  __syncthreads();   // B5: WlA(Wv0) landed
  stage_glds_h(WlB, Wv + 8192, tid);   // Wv1 -> WlB
  gemm4_s(WlA, af, lm, quad, acc);
  store_sl4(Xl, acc, vbias, wv, lm, quad, 0);
  __syncthreads();   // B6: WlB(Wv1) landed
  stage_glds_h(WlA, Wq, tid);          // Wq0 -> WlA
  gemm4_s(WlB, af, lm, quad, acc);
  store_sl4(Xl, acc, vbias, wv, lm, quad, 64);
  write_hs_s(Xl, Vb, rb, 12, tid);
  __syncthreads();   // B7: WlA(Wq0) landed
  stage_glds_h(WlB, Wq + 8192, tid);   // Wq1 -> WlB
  gemm4_s(WlA, af, lm, quad, acc);
  store_sl4(Xl, acc, qbias, wv, lm, quad, 0);
  __syncthreads();   // B8: WlB(Wq1) landed
  gemm4_s(WlB, af, lm, quad, acc);
  store_sl4(Xl, acc, qbias, wv, lm, quad, 64);
  write_hs_s(Xl, Qb, rb, 12, tid);
}

// ---------------------------------------------------------------------------
extern "C" void kernel_launch(void* const* d_in, const int* in_sizes, int n_in,
                              void* d_out, int out_size, void* d_ws,
                              size_t ws_size, hipStream_t stream) {
  const float* cx    = (const float*)d_in[0];
  const float* value = (const float*)d_in[1];
  const float* mask  = (const float*)d_in[2];
  const float* iff_w = (const float*)d_in[4];
  const float* iff_b = (const float*)d_in[5];
  const float* indp  = (const float*)d_in[6];
  const float* q0w = (const float*)d_in[7];  const float* q0b = (const float*)d_in[8];
  const float* k0w = (const float*)d_in[9];  const float* k0b = (const float*)d_in[10];
  const float* v0w = (const float*)d_in[11]; const float* v0b = (const float*)d_in[12];
  const float* o0w = (const float*)d_in[13]; const float* o0b = (const float*)d_in[14];
  const float* q1w = (const float*)d_in[15]; const float* q1b = (const float*)d_in[16];
  const float* k1w = (const float*)d_in[17]; const float* k1b = (const float*)d_in[18];
  const float* v1w = (const float*)d_in[19]; const float* v1b = (const float*)d_in[20];
  const float* o1w = (const float*)d_in[21]; const float* o1b = (const float*)d_in[22];

  char* ws = (char*)d_ws;
  short* Wt    = (short*)ws;  ws += (size_t)24 * 16384 * 2;
  int*   order = (int*)ws;    ws += (size_t)NBATCH * OBS * 4;
  float* mk_g  = (float*)ws;  ws += (size_t)NBATCH * OBS * 4;
  float* Z     = (float*)ws;  ws += (size_t)NBATCH * OBS * DK * 4;
  short* Qb    = (short*)ws;  ws += (size_t)NBATCH * OBS * DK * 2;
  short* Kb    = (short*)ws;  ws += (size_t)NBATCH * OBS * DK * 2;
  short* Vb    = (short*)ws;  ws += (size_t)NBATCH * OBS * DK * 2;
  short* Ob    = (short*)ws;  ws += (size_t)NBATCH * OBS * DK * 2;
  short* qh_b  = (short*)ws;  ws += (size_t)3 * 128 * DK * 2;
  short* khb   = (short*)ws;  ws += (size_t)NBATCH * NH * 128 * DH * 2;
  short* vhb   = (short*)ws;  ws += (size_t)NBATCH * NH * 128 * DH * 2;
  float* Opart = (float*)ws;  ws += (size_t)8 * 64 * 128 * 32 * 4;
  float* mpart = (float*)ws;  ws += (size_t)8 * 64 * 128 * 4;
  float* lpart = (float*)ws;  ws += (size_t)8 * 64 * 128 * 4;

  float* outZ  = (float*)d_out;
  float* outMk = outZ + (size_t)NBATCH * OBS * DK;

  prep_build_kernel<<<40, 1024, 0, stream>>>(q0w, k0w, v0w, o0w, q1w, k1w,
                                             v1w, o1w, Wt, mask, order, mk_g,
                                             outMk);

  const short* W[3][8];
  for (int l = 0; l < 3; l++)
    for (int wi = 0; wi < 8; wi++) W[l][wi] = Wt + (size_t)(l * 8 + wi) * 16384;

  fusedA_kernel<<<1030, 256, 0, stream>>>(
      order, mk_g, cx, value, iff_w, iff_b, Z,
      W[0][1], k0b, Kb, W[0][2], v0b, Vb, W[0][4], q1b, Qb,
      indp, Wt, q0b, qh_b);

  for (int l = 0; l < 3; l++) {
    attn1_kernel<<<dim3(64, 8), 256, 0, stream>>>(
        qh_b + (size_t)l * 16384, Kb, Vb, mk_g, Opart, mpart, lpart);
    fusedB_kernel<<<32, 1024, 0, stream>>>(
        Opart, mpart, lpart, qh_b + (size_t)l * 16384,
        W[l][3], o0b + (size_t)l * 128,
        W[l][5], k1b + (size_t)l * 128,
        W[l][6], v1b + (size_t)l * 128, khb, vhb);
    attn2_kernel<<<dim3(64, 64), 256, 0, stream>>>(Qb, khb, vhb, Ob);
    if (l < 2) {
      fusedC_kernel<<<1024, 256, 0, stream>>>(
          Ob, W[l][7], o1b + (size_t)l * 128, mk_g, Z, Z,
          W[l + 1][1], k0b + (size_t)(l + 1) * 128, Kb,
          W[l + 1][2], v0b + (size_t)(l + 1) * 128, Vb,
          W[l + 1][4], q1b + (size_t)(l + 1) * 128, Qb);
    } else {
      fusedC_kernel<<<1024, 256, 0, stream>>>(
          Ob, W[l][7], o1b + (size_t)l * 128, mk_g, Z, outZ,
          nullptr, nullptr, nullptr, nullptr, nullptr, nullptr,
          nullptr, nullptr, nullptr);
    }
  }
}

// Round 14
// 444.168 us; speedup vs baseline: 1.2436x; 1.0052x over previous
//
#include <hip/hip_runtime.h>
#include <math.h>

#define NBATCH 16
#define SEQL   512
#define DIM    41
#define LDFLAT (SEQL*DIM)   // 20992
#define OBS    4096
#define DK     128
#define NH     4
#define DH     32

typedef short bf16x8 __attribute__((ext_vector_type(8)));
typedef short short8v __attribute__((ext_vector_type(8)));
typedef float floatx4 __attribute__((ext_vector_type(4)));

__device__ __forceinline__ short f2bf(float f) {
  union { float f; unsigned u; } v;
  v.f = f;
  unsigned r = (v.u + 0x7fffu + ((v.u >> 16) & 1u)) >> 16;
  return (short)r;
}
__device__ __forceinline__ float bf2f(short s) {
  union { unsigned u; float f; } v;
  v.u = ((unsigned)(unsigned short)s) << 16;
  return v.f;
}

// ---- R23 (FINAL): exact revert to R21 — verified session best (446.5us) ---
// R22 post-mortem: extending glds to fusedC's Ob activation tile introduced
// a replay-timing race (first call correct, graph replays diverged absmax
// 7.4). The pre-swizzled index math is bijective/consistent (first call
// passed), so the hazard is in the in-flight glds(Xl<-Ob) stream vs the
// epilogue's in-place O->newZ RMW on the same LDS buffer — a hazard class
// the read-only weight buffers never hit. Reverted per rigor discipline.
// R21 ladder: 458.2 (R15) -> 446.5 via __builtin_amdgcn_global_load_lds
// weight staging (width 16, producer-side pre-swizzled Wt), which removed
// the per-phase staged-load wait + ds_write tail. Counters clean
// (FETCH 2.2MB / WRITE 85MB, no spills).

__device__ __forceinline__ int swz(int row, int col) {  // col in shorts
  return row * 128 + ((((col >> 3) ^ row) & 15) << 3) + (col & 7);
}

// ---- direct global->LDS 16B copy (wave-uniform LDS base + lane*16) ----
__device__ __forceinline__ void glds16(const short* g, short* l) {
  __builtin_amdgcn_global_load_lds(
      (const __attribute__((address_space(1))) void*)g,
      (__attribute__((address_space(3))) void*)l, 16, 0, 0);
}
// 256-thread half-weight (16KB: 8192 shorts), Wt pre-swizzled => linear dest
__device__ __forceinline__ void stage_glds_h(short* Wl,
                                             const short* __restrict__ W,
                                             int tid) {
  int wb = (tid >> 6) * 512;   // wave-uniform LDS base (shorts)
#pragma unroll
  for (int k = 0; k < 4; k++)
    glds16(&W[(size_t)tid * 8 + (size_t)k * 2048], &Wl[wb + k * 2048]);
}
// 1024-thread full-weight (32KB: 16384 shorts)
__device__ __forceinline__ void stage_glds_f(short* Wl,
                                             const short* __restrict__ W,
                                             int tid) {
  int wb = (tid >> 6) * 512;
#pragma unroll
  for (int k = 0; k < 2; k++)
    glds16(&W[(size_t)tid * 8 + (size_t)k * 8192], &Wl[wb + k * 8192]);
}

// 4-nt GEMM against a 64-row weight buffer (one half)
__device__ __forceinline__ void gemm4_s(const short* Wl, const bf16x8 af[4],
                                        int lm, int quad, floatx4 acc[4]) {
#pragma unroll
  for (int nt = 0; nt < 4; nt++) acc[nt] = (floatx4){0.f, 0.f, 0.f, 0.f};
#pragma unroll
  for (int kc = 0; kc < 4; kc++) {
    bf16x8 a = af[kc];
#pragma unroll
    for (int nt = 0; nt < 4; nt++) {
      bf16x8 b = *(const bf16x8*)&Wl[swz(nt * 16 + lm, kc * 32 + quad * 8)];
      acc[nt] = __builtin_amdgcn_mfma_f32_16x16x32_bf16(a, b, acc[nt], 0, 0, 0);
    }
  }
}
// 2-nt GEMM against a full 128-row buffer, col-quarter colq
__device__ __forceinline__ void gemm2_s(const short* Wl, const bf16x8 af[4],
                                        int colq, int lm, int quad,
                                        floatx4 acc[2]) {
#pragma unroll
  for (int nt = 0; nt < 2; nt++) acc[nt] = (floatx4){0.f, 0.f, 0.f, 0.f};
#pragma unroll
  for (int kc = 0; kc < 4; kc++) {
    bf16x8 a = af[kc];
#pragma unroll
    for (int nt = 0; nt < 2; nt++) {
      bf16x8 b = *(const bf16x8*)&Wl[swz(colq * 32 + nt * 16 + lm,
                                         kc * 32 + quad * 8)];
      acc[nt] = __builtin_amdgcn_mfma_f32_16x16x32_bf16(a, b, acc[nt], 0, 0, 0);
    }
  }
}
__device__ __forceinline__ void load_af_s(const short* Xl, int strip, int lm,
                                          int quad, bf16x8 af[4]) {
#pragma unroll
  for (int kc = 0; kc < 4; kc++)
    af[kc] = *(const bf16x8*)&Xl[swz(strip * 16 + lm, kc * 32 + quad * 8)];
}
// stage bias-added bf16 half-result (wave-local rows), cols colbase..+63
__device__ __forceinline__ void store_sl4(short* Sl, const floatx4 acc[4],
                                          const float* __restrict__ bias,
                                          int wv, int lm, int quad,
                                          int colbase) {
#pragma unroll
  for (int nt = 0; nt < 4; nt++) {
    int col = colbase + nt * 16 + lm;
    float bn = bias[col];
#pragma unroll
    for (int r = 0; r < 4; r++)
      Sl[swz(wv * 16 + quad * 4 + r, col)] = f2bf(acc[nt][r] + bn);
  }
}
// write Sl rows rb..rb+63 to head-split out (wave-local rows: rr=tid>>2)
__device__ __forceinline__ void write_hs_s(const short* Sl,
                                           short* __restrict__ out, int rb,
                                           int nshift, int tid) {
  int rr = tid >> 2, hh = tid & 3;
  int r = rb + rr;
  int bb = r >> nshift, nn = r & ((1 << nshift) - 1);
  size_t o = (((size_t)(bb * NH + hh) << nshift) + nn) * 32;
#pragma unroll
  for (int j = 0; j < 4; j++)
    *(int4*)&out[o + j * 8] = *(int4*)&Sl[swz(rr, hh * 32 + j * 8)];
}
// 1024-thread quarter write: wave (strip,colq) writes its own 16 rows x head
__device__ __forceinline__ void write_hs_q(const short* Sl,
                                           short* __restrict__ out, int rb,
                                           int nshift, int strip, int colq,
                                           int lane) {
  int rr = strip * 16 + (lane >> 2);
  int r = rb + rr;
  int bb = r >> nshift, nn = r & ((1 << nshift) - 1);
  size_t o = (((size_t)(bb * NH + colq) << nshift) + nn) * 32 + (lane & 3) * 8;
  *(int4*)&out[o] = *(const int4*)&Sl[swz(rr, colq * 32 + (lane & 3) * 8)];
}

// ---------------------------------------------------------------------------
// Kernel: merged weight-prep (blocks 0..23) + stable-order scan (blocks 24..39)
// R21: Wt written PRE-SWIZZLED so linear glds staging yields the swz layout.
// ---------------------------------------------------------------------------
__global__ __launch_bounds__(1024) void prep_build_kernel(
    const float* __restrict__ q0w, const float* __restrict__ k0w,
    const float* __restrict__ v0w, const float* __restrict__ o0w,
    const float* __restrict__ q1w, const float* __restrict__ k1w,
    const float* __restrict__ v1w, const float* __restrict__ o1w,
    short* __restrict__ Wt,
    const float* __restrict__ mask, int* __restrict__ order,
    float* __restrict__ mk_out, float* __restrict__ mk_out2) {
  __shared__ float Tl[128 * 132];
  __shared__ int wsums[16];
  __shared__ int s_total_ones;
  __shared__ int s_chunk_ones;
  __shared__ int s_ones_base;
  __shared__ int s_zeros_base;
  int tid = threadIdx.x;

  if (blockIdx.x < 24) {
    int id = blockIdx.x, l = id >> 3, wi = id & 7;
    const float* s;
    switch (wi) {
      case 0: s = q0w; break; case 1: s = k0w; break;
      case 2: s = v0w; break; case 3: s = o0w; break;
      case 4: s = q1w; break; case 5: s = k1w; break;
      case 6: s = v1w; break; default: s = o1w; break;
    }
    s += (size_t)l * 16384;
    for (int i = tid * 4; i < 16384; i += 4096) {
      int k = i >> 7, n = i & 127;
      float4 x = *(const float4*)&s[i];
      Tl[k * 132 + n + 0] = x.x; Tl[k * 132 + n + 1] = x.y;
      Tl[k * 132 + n + 2] = x.z; Tl[k * 132 + n + 3] = x.w;
    }
    __syncthreads();
    short* dst = Wt + (size_t)id * 16384;
    int n = tid >> 3, k0 = (tid & 7) * 16;
    for (int jc = 0; jc < 2; jc++) {
      short8v t;
#pragma unroll
      for (int j = 0; j < 8; j++) t[j] = f2bf(Tl[(k0 + jc * 8 + j) * 132 + n]);
      // pre-swizzled: segment-aligned cols stay contiguous (16B store OK)
      *(short8v*)&dst[swz(n, k0 + jc * 8)] = t;
    }
    return;
  }

  int b = blockIdx.x - 24;
  const float* m = mask + (size_t)b * LDFLAT;
  int lane = tid & 63, w = tid >> 6;

  int cnt = 0;
  for (int j = tid; j < LDFLAT; j += 1024) cnt += (m[j] > 0.f) ? 1 : 0;
  for (int off = 32; off > 0; off >>= 1) cnt += __shfl_xor(cnt, off);
  if (lane == 0) wsums[w] = cnt;
  __syncthreads();
  if (tid == 0) {
    int t = 0;
    for (int i = 0; i < 16; i++) t += wsums[i];
    s_total_ones = t; s_ones_base = 0; s_zeros_base = 0;
  }
  __syncthreads();
  int total_ones = s_total_ones;

  for (int c0 = 0; c0 < LDFLAT; c0 += 1024) {
    __syncthreads();
    int j = c0 + tid;
    bool valid = (j < LDFLAT);
    float mv = valid ? m[j] : 0.f;
    int one = (valid && mv > 0.f) ? 1 : 0;
    int v = one;
    for (int off = 1; off < 64; off <<= 1) {
      int t = __shfl_up(v, (unsigned)off);
      if (lane >= off) v += t;
    }
    if (lane == 63) wsums[w] = v;
    __syncthreads();
    if (tid == 0) {
      int run = 0;
      for (int i = 0; i < 16; i++) { int t = wsums[i]; wsums[i] = run; run += t; }
      s_chunk_ones = run;
    }
    __syncthreads();
    int ones_before = (v - one) + wsums[w];
    int ob = s_ones_base, zb = s_zeros_base, chunk_ones = s_chunk_ones;
    int rem = LDFLAT - c0;
    int chunk_valid = rem < 1024 ? rem : 1024;
    int valid_before = tid < rem ? tid : rem;
    if (valid) {
      int pos = one ? (ob + ones_before)
                    : (total_ones + zb + (valid_before - ones_before));
      if (pos < OBS) {
        order[b * OBS + pos] = j;
        mk_out[b * OBS + pos] = mv;
        mk_out2[b * OBS + pos] = mv;
      }
    }
    __syncthreads();
    if (tid == 0) {
      s_ones_base = ob + chunk_ones;
      s_zeros_base = zb + (chunk_valid - chunk_ones);
    }
  }
}

// ---------------------------------------------------------------------------
// Kernel: fusedA — embed (layer-0 Z) + K0/V0/Q1 projections (blocks 0..1023)
//                + ind-point Q projections for all 3 layers (blocks 1024..1029)
// R21: glds staging; each glds issued right after the barrier freeing its
// dest buffer; 6 barriers unchanged.
// ---------------------------------------------------------------------------
__global__ __launch_bounds__(256, 3) void fusedA_kernel(
    const int* __restrict__ order, const float* __restrict__ mk_g,
    const float* __restrict__ cx, const float* __restrict__ value,
    const float* __restrict__ iff_w, const float* __restrict__ iff_b,
    float* __restrict__ Z,
    const short* __restrict__ Wk, const float* __restrict__ kbias,
    short* __restrict__ Kb,
    const short* __restrict__ Wv, const float* __restrict__ vbias,
    short* __restrict__ Vb,
    const short* __restrict__ Wq, const float* __restrict__ qbias,
    short* __restrict__ Qb,
    const float* __restrict__ indp, const short* __restrict__ WtAll,
    const float* __restrict__ q0b_all, short* __restrict__ qh_b) {
  __shared__ __align__(16) short Xl[64 * 128];
  __shared__ __align__(16) short WlA[64 * 128];
  __shared__ __align__(16) short WlB[64 * 128];
  int tid = threadIdx.x;
  int wv = tid >> 6, lane = tid & 63, lm = lane & 15, quad = lane >> 4;
  int r_l = lane >> 2, seg = lane & 3;
  int lrow = wv * 16 + r_l;      // wave-local row this lane helps fill

  if (blockIdx.x >= 1024) {
    // ---- qh_proj path: both halves glds'd upfront, 1 barrier ----
    int id = blockIdx.x - 1024;
    int l = id >> 1, rbq = (id & 1) * 64;
    const float* X = indp + (size_t)l * 16384 + (size_t)rbq * 128;
    const short* W = WtAll + (size_t)(l * 8) * 16384;  // q0w^T (pre-swz)
    const float* bias = q0b_all + (size_t)l * 128;
    short* out = qh_b + (size_t)l * 16384;
    stage_glds_h(WlA, W, tid);
    stage_glds_h(WlB, W + 8192, tid);
    const float* Xr = X + (size_t)lrow * 128;
#pragma unroll
    for (int jj = 0; jj < 8; jj++) {
      int col = seg * 32 + jj * 4;
      float4 x = *(const float4*)&Xr[col];
      *(short4*)&Xl[swz(lrow, col)] =
          make_short4(f2bf(x.x), f2bf(x.y), f2bf(x.z), f2bf(x.w));
    }
    __syncthreads();   // drains glds (vmcnt) + Xl writes
    bf16x8 af[4];
    load_af_s(Xl, wv, lm, quad, af);
    floatx4 acc[4];
    gemm4_s(WlA, af, lm, quad, acc);
    store_sl4(Xl, acc, bias, wv, lm, quad, 0);
    gemm4_s(WlB, af, lm, quad, acc);
    store_sl4(Xl, acc, bias, wv, lm, quad, 64);
    write_hs_s(Xl, out, rbq, 7, tid);
    return;
  }

  int rb = blockIdx.x * 64;
  stage_glds_h(WlA, Wk, tid);        // Wk0 -> WlA (dest fresh)
  int grow = rb + lrow;
  int bb = grow >> 12;
  int j = order[grow];               // 4 lanes/row share -> broadcast-coalesced
  int l = j / DIM, d = j - l * DIM;
  float t = cx[bb * SEQL + l];
  float u = value[(size_t)bb * LDFLAT + j];
  float mkv = mk_g[grow];
#pragma unroll
  for (int jj = 0; jj < 8; jj++) {
    int col = seg * 32 + jj * 4;
    float4 w0 = *(const float4*)&iff_w[d * DK + col];
    float4 w1 = *(const float4*)&iff_w[41 * DK + col];
    float4 w2 = *(const float4*)&iff_w[42 * DK + col];
    float4 b4 = *(const float4*)&iff_b[col];
    float4 z;
    z.x = fmaxf(w0.x + t * w1.x + u * w2.x + b4.x, 0.f) * mkv;
    z.y = fmaxf(w0.y + t * w1.y + u * w2.y + b4.y, 0.f) * mkv;
    z.z = fmaxf(w0.z + t * w1.z + u * w2.z + b4.z, 0.f) * mkv;
    z.w = fmaxf(w0.w + t * w1.w + u * w2.w + b4.w, 0.f) * mkv;
    *(float4*)&Z[(size_t)grow * DK + col] = z;
    *(short4*)&Xl[swz(lrow, col)] =
        make_short4(f2bf(z.x), f2bf(z.y), f2bf(z.z), f2bf(z.w));
  }
  __syncthreads();   // B1: Xl(embed) + WlA(Wk0) landed
  stage_glds_h(WlB, Wk + 8192, tid);   // Wk1 -> WlB (dest fresh)
  bf16x8 af[4];
  load_af_s(Xl, wv, lm, quad, af);   // af cached for all GEMMs
  floatx4 acc[4];
  gemm4_s(WlA, af, lm, quad, acc);
  store_sl4(Xl, acc, kbias, wv, lm, quad, 0);
  __syncthreads();   // B2: WlB(Wk1) landed; WlA reads done
  stage_glds_h(WlA, Wv, tid);          // Wv0 -> WlA (freed at B2)
  gemm4_s(WlB, af, lm, quad, acc);
  store_sl4(Xl, acc, kbias, wv, lm, quad, 64);
  write_hs_s(Xl, Kb, rb, 12, tid);
  __syncthreads();   // B3: WlA(Wv0) landed; WlB reads done
  stage_glds_h(WlB, Wv + 8192, tid);   // Wv1 -> WlB (freed at B3)
  gemm4_s(WlA, af, lm, quad, acc);
  store_sl4(Xl, acc, vbias, wv, lm, quad, 0);
  __syncthreads();   // B4: WlB(Wv1) landed
  stage_glds_h(WlA, Wq, tid);          // Wq0 -> WlA (freed at B4)
  gemm4_s(WlB, af, lm, quad, acc);
  store_sl4(Xl, acc, vbias, wv, lm, quad, 64);
  write_hs_s(Xl, Vb, rb, 12, tid);
  __syncthreads();   // B5: WlA(Wq0) landed
  stage_glds_h(WlB, Wq + 8192, tid);   // Wq1 -> WlB (freed at B5)
  gemm4_s(WlA, af, lm, quad, acc);
  store_sl4(Xl, acc, qbias, wv, lm, quad, 0);
  __syncthreads();   // B6: WlB(Wq1) landed
  gemm4_s(WlB, af, lm, quad, acc);
  store_sl4(Xl, acc, qbias, wv, lm, quad, 64);
  write_hs_s(Xl, Qb, rb, 12, tid);
}

// ---------------------------------------------------------------------------
// Kernel: MAB1 attention (bf16), flash over 8 key splits. grid (64, 8).
// R15: K/V chunk register prefetch; Vtc stride 74 (bank-conflict-free).
// ---------------------------------------------------------------------------
__global__ __launch_bounds__(256) void attn1_kernel(
    const short* __restrict__ Qh,   // (NH,128,32) bf16, layer base
    const short* __restrict__ Kh, const short* __restrict__ Vh,
    const float* __restrict__ mk,
    float* __restrict__ Opart, float* __restrict__ mpart,
    float* __restrict__ lpart) {
  __shared__ __align__(16) short Ql[128 * 40];
  __shared__ __align__(16) short Kc[64 * 40];
  __shared__ __align__(16) short Vtc[32 * 74];
  __shared__ __align__(16) short Pl[128 * 72];
  __shared__ float mkc[64];
  int bh = blockIdx.x;
  int b = bh >> 2, h = bh & 3;
  int ks = blockIdx.y;
  int tid = threadIdx.x;
  int wv = tid >> 6, lane = tid & 63, lm = lane & 15, quad = lane >> 4;

  const float scale = 0.08838834764831845f;
  const short* kbase = Kh + ((size_t)bh * OBS + ks * 512) * 32;
  const short* vbase = Vh + ((size_t)bh * OBS + ks * 512) * 32;
  const float* mkb = mk + (size_t)b * OBS + ks * 512;

  // prefetch chunk 0 K/V + mk into registers (overlaps Q staging)
  int i0 = tid * 8;
  int r0 = i0 >> 5, cv = i0 & 31;
  int4 kreg = *(const int4*)&kbase[i0];
  int4 vreg = *(const int4*)&vbase[i0];
  float mreg = (tid < 64) ? mkb[tid] : 0.f;

  const short* qbg = Qh + (size_t)h * 128 * 32;
  for (int i = tid * 8; i < 128 * 32; i += 2048) {
    int r = i >> 5, c = i & 31;
    *(int4*)&Ql[r * 40 + c] = *(const int4*)&qbg[i];
  }
  __syncthreads();
  bf16x8 aq[2];
  aq[0] = *(bf16x8*)&Ql[(wv * 32 + lm) * 40 + quad * 8];
  aq[1] = *(bf16x8*)&Ql[(wv * 32 + 16 + lm) * 40 + quad * 8];

  float m_i[2][4], l_i[2][4];
  floatx4 oacc[2][2];
#pragma unroll
  for (int mt = 0; mt < 2; mt++) {
#pragma unroll
    for (int r = 0; r < 4; r++) { m_i[mt][r] = -1e30f; l_i[mt][r] = 0.f; }
    oacc[mt][0] = (floatx4){0.f, 0.f, 0.f, 0.f};
    oacc[mt][1] = (floatx4){0.f, 0.f, 0.f, 0.f};
  }

  for (int ch = 0; ch < 8; ch++) {
    __syncthreads();   // prev chunk's Kc/Vtc reads done
    *(int4*)&Kc[r0 * 40 + cv] = kreg;
    {
      short* vv = (short*)&vreg;
#pragma unroll
      for (int j = 0; j < 8; j++) Vtc[(cv + j) * 74 + r0] = vv[j];
    }
    if (tid < 64) mkc[tid] = mreg;
    if (ch < 7) {      // issue next chunk's loads; latency hides under compute
      kreg = *(const int4*)&kbase[(ch + 1) * 2048 + i0];
      vreg = *(const int4*)&vbase[(ch + 1) * 2048 + i0];
      if (tid < 64) mreg = mkb[(ch + 1) * 64 + tid];
    }
    __syncthreads();   // Kc/Vtc/mkc ready

    floatx4 sf[2][4];
#pragma unroll
    for (int nt = 0; nt < 4; nt++) {
      bf16x8 bfrag = *(bf16x8*)&Kc[(nt * 16 + lm) * 40 + quad * 8];
      floatx4 z = {0.f, 0.f, 0.f, 0.f};
      sf[0][nt] = __builtin_amdgcn_mfma_f32_16x16x32_bf16(aq[0], bfrag, z, 0, 0, 0);
      sf[1][nt] = __builtin_amdgcn_mfma_f32_16x16x32_bf16(aq[1], bfrag, z, 0, 0, 0);
    }
#pragma unroll
    for (int nt = 0; nt < 4; nt++) {
      float mkv = mkc[nt * 16 + lm];
      bool ok = mkv > 0.f;
#pragma unroll
      for (int mt = 0; mt < 2; mt++)
#pragma unroll
        for (int r = 0; r < 4; r++)
          sf[mt][nt][r] = ok ? sf[mt][nt][r] * scale : -1e10f;
    }
#pragma unroll
    for (int mt = 0; mt < 2; mt++) {
#pragma unroll
      for (int r = 0; r < 4; r++) {
        float mx = fmaxf(fmaxf(sf[mt][0][r], sf[mt][1][r]),
                         fmaxf(sf[mt][2][r], sf[mt][3][r]));
        mx = fmaxf(mx, __shfl_xor(mx, 1));
        mx = fmaxf(mx, __shfl_xor(mx, 2));
        mx = fmaxf(mx, __shfl_xor(mx, 4));
        mx = fmaxf(mx, __shfl_xor(mx, 8));
        float mn = fmaxf(m_i[mt][r], mx);
        float al = __expf(m_i[mt][r] - mn);
        float ps = 0.f;
#pragma unroll
        for (int nt = 0; nt < 4; nt++) {
          float p = __expf(sf[mt][nt][r] - mn);
          sf[mt][nt][r] = p;
          ps += p;
        }
        ps += __shfl_xor(ps, 1);
        ps += __shfl_xor(ps, 2);
        ps += __shfl_xor(ps, 4);
        ps += __shfl_xor(ps, 8);
        l_i[mt][r] = l_i[mt][r] * al + ps;
        m_i[mt][r] = mn;
        oacc[mt][0] *= al;
        oacc[mt][1] *= al;
      }
    }
#pragma unroll
    for (int mt = 0; mt < 2; mt++)
#pragma unroll
      for (int nt = 0; nt < 4; nt++)
#pragma unroll
        for (int r = 0; r < 4; r++)
          Pl[(wv * 32 + mt * 16 + quad * 4 + r) * 72 + nt * 16 + lm] =
              f2bf(sf[mt][nt][r]);
#pragma unroll
    for (int kc = 0; kc < 2; kc++) {
      bf16x8 vf0 = *(bf16x8*)&Vtc[lm * 74 + kc * 32 + quad * 8];
      bf16x8 vf1 = *(bf16x8*)&Vtc[(16 + lm) * 74 + kc * 32 + quad * 8];
#pragma unroll
      for (int mt = 0; mt < 2; mt++) {
        bf16x8 pf = *(bf16x8*)&Pl[(wv * 32 + mt * 16 + lm) * 72 + kc * 32 + quad * 8];
        oacc[mt][0] = __builtin_amdgcn_mfma_f32_16x16x32_bf16(pf, vf0, oacc[mt][0], 0, 0, 0);
        oacc[mt][1] = __builtin_amdgcn_mfma_f32_16x16x32_bf16(pf, vf1, oacc[mt][1], 0, 0, 0);
      }
    }
  }
  float* ob = Opart + (size_t)(ks * 64 + bh) * 128 * 32;
#pragma unroll
  for (int mt = 0; mt < 2; mt++) {
#pragma unroll
    for (int r = 0; r < 4; r++) {
      int row = wv * 32 + mt * 16 + quad * 4 + r;
      ob[(size_t)row * 32 + lm] = oacc[mt][0][r];
      ob[(size_t)row * 32 + 16 + lm] = oacc[mt][1][r];
      if (lm == 0) {
        mpart[(size_t)(ks * 64 + bh) * 128 + row] = m_i[mt][r];
        lpart[(size_t)(ks * 64 + bh) * 128 + row] = l_i[mt][r];
      }
    }
  }
}

// ---------------------------------------------------------------------------
// Kernel: fusedB — attn1 combine + fc_o + K1/V1 projections. grid 32 x 1024.
// R21: glds staging (dest freed before each issue); 5 barriers unchanged.
// ---------------------------------------------------------------------------
__global__ __launch_bounds__(1024) void fusedB_kernel(
    const float* __restrict__ Opart, const float* __restrict__ mpart,
    const float* __restrict__ lpart, const short* __restrict__ qh,
    const short* __restrict__ Wo, const float* __restrict__ obias,
    const short* __restrict__ Wk, const float* __restrict__ kbias,
    const short* __restrict__ Wv, const float* __restrict__ vbias,
    short* __restrict__ khb, short* __restrict__ vhb) {
  __shared__ __align__(16) short Xl[64 * 128];
  __shared__ __align__(16) short WlA[128 * 128];
  __shared__ __align__(16) short WlB[128 * 128];
  int tid = threadIdx.x;
  int rb = blockIdx.x * 64;           // row in 2048 = b*128 + n
  int b = rb >> 7, n0 = rb & 127;
  int wv = tid >> 6, lane = tid & 63, lm = lane & 15, quad = lane >> 4;
  int strip = wv & 3, colq = wv >> 2;
  stage_glds_f(WlA, Wo, tid);         // Wo -> WlA (dest fresh)
  // combine: 256 (row,head) pairs x 8 lanes = 2 passes of 1024
#pragma unroll
  for (int p = 0; p < 2; p++) {
    int slot = p * 1024 + tid;
    int pair = slot >> 3;
    int hh = pair & 3, rr = pair >> 2;
    int c4 = (slot & 7) * 4;
    int n = n0 + rr;
    int bh = b * 4 + hh;
    float mv[8], lv[8], m = -1e30f;
#pragma unroll
    for (int s = 0; s < 8; s++) {
      mv[s] = mpart[(size_t)(s * 64 + bh) * 128 + n];
      lv[s] = lpart[(size_t)(s * 64 + bh) * 128 + n];
      m = fmaxf(m, mv[s]);
    }
    float l = 0.f, oa0 = 0.f, oa1 = 0.f, oa2 = 0.f, oa3 = 0.f;
#pragma unroll
    for (int s = 0; s < 8; s++) {
      float w = __expf(mv[s] - m);
      l += lv[s] * w;
      float4 v = *(const float4*)&Opart[((size_t)(s * 64 + bh) * 128 + n) * 32 + c4];
      oa0 += v.x * w; oa1 += v.y * w; oa2 += v.z * w; oa3 += v.w * w;
    }
    float li = 1.f / l;
    int2 qi = *(const int2*)&qh[((size_t)hh * 128 + n) * 32 + c4];
    const short* qs = (const short*)&qi;
    short4 o4;
    o4.x = f2bf(bf2f(qs[0]) + oa0 * li);
    o4.y = f2bf(bf2f(qs[1]) + oa1 * li);
    o4.z = f2bf(bf2f(qs[2]) + oa2 * li);
    o4.w = f2bf(bf2f(qs[3]) + oa3 * li);
    *(short4*)&Xl[swz(rr, hh * 32 + c4)] = o4;
  }
  __syncthreads();   // B1: Xl(O) + WlA(Wo) landed
  bf16x8 afO[4];
  load_af_s(Xl, strip, lm, quad, afO);
  __syncthreads();   // B1b: all O reads done before H writes
  stage_glds_f(WlB, Wk, tid);         // Wk -> WlB (dest fresh)
  floatx4 acc[2];
  gemm2_s(WlA, afO, colq, lm, quad, acc);
  // H = O + relu(acc + bias): in-place on this wave's (strip,colq) quarter
#pragma unroll
  for (int nt = 0; nt < 2; nt++) {
    int col = colq * 32 + nt * 16 + lm;
    float bn = obias[col];
#pragma unroll
    for (int r = 0; r < 4; r++) {
      int row = strip * 16 + quad * 4 + r;
      float ov = bf2f(Xl[swz(row, col)]);
      Xl[swz(row, col)] = f2bf(ov + fmaxf(acc[nt][r] + bn, 0.f));
    }
  }
  __syncthreads();   // B2: Xl(H) complete + WlB(Wk) landed; WlA reads done
  bf16x8 afH[4];
  load_af_s(Xl, strip, lm, quad, afH);
  __syncthreads();   // B2b: all H reads done before K-result writes
  stage_glds_f(WlA, Wv, tid);         // Wv -> WlA (freed at B2)
  gemm2_s(WlB, afH, colq, lm, quad, acc);
#pragma unroll
  for (int nt = 0; nt < 2; nt++) {
    int col = colq * 32 + nt * 16 + lm;
    float bn = kbias[col];
#pragma unroll
    for (int r = 0; r < 4; r++)
      Xl[swz(strip * 16 + quad * 4 + r, col)] = f2bf(acc[nt][r] + bn);
  }
  write_hs_q(Xl, khb, rb, 7, strip, colq, lane);   // wave-local quarter
  __syncthreads();   // B3: WlA(Wv) landed; all khb reads done before V writes
  gemm2_s(WlA, afH, colq, lm, quad, acc);
#pragma unroll
  for (int nt = 0; nt < 2; nt++) {
    int col = colq * 32 + nt * 16 + lm;
    float bn = vbias[col];
#pragma unroll
    for (int r = 0; r < 4; r++)
      Xl[swz(strip * 16 + quad * 4 + r, col)] = f2bf(acc[nt][r] + bn);
  }
  write_hs_q(Xl, vhb, rb, 7, strip, colq, lane);
}

// ---------------------------------------------------------------------------
// Kernel: MAB2 attention, register softmax. grid (64, 64). LDS ~42 KB.
// ---------------------------------------------------------------------------
__global__ __launch_bounds__(256) void attn2_kernel(
    const short* __restrict__ Qh, const short* __restrict__ Kh,
    const short* __restrict__ Vh, short* __restrict__ O) {
  __shared__ __align__(16) short Kl[128 * 40];
  __shared__ __align__(16) short Vt[32 * 136];
  __shared__ __align__(16) short Ql[64 * 40];
  __shared__ __align__(16) short Pl[64 * 136];
  int bh = blockIdx.x;
  int b = bh >> 2, h = bh & 3;
  int q0 = blockIdx.y * 64;
  int tid = threadIdx.x;
  int wv = tid >> 6, lane = tid & 63, lm = lane & 15, quad = lane >> 4;
  const short* kb = Kh + (size_t)bh * 128 * 32;
  const short* vb = Vh + (size_t)bh * 128 * 32;
  const short* qb = Qh + ((size_t)bh * OBS + q0) * 32;

  for (int i = tid * 8; i < 128 * 32; i += 2048) {
    int r = i >> 5, c = i & 31;
    *(int4*)&Kl[r * 40 + c] = *(const int4*)&kb[i];
  }
  for (int i = tid * 8; i < 64 * 32; i += 2048) {
    int r = i >> 5, c = i & 31;
    *(int4*)&Ql[r * 40 + c] = *(const int4*)&qb[i];
  }
  for (int i = tid * 8; i < 128 * 32; i += 2048) {
    int r = i >> 5, c = i & 31;
    int4 vv4 = *(const int4*)&vb[i];
    short* vv = (short*)&vv4;
#pragma unroll
    for (int j = 0; j < 8; j++) Vt[(c + j) * 136 + r] = vv[j];
  }
  __syncthreads();

  const float scale = 0.08838834764831845f;
  bf16x8 afrag = *(bf16x8*)&Ql[(wv * 16 + lm) * 40 + quad * 8];
  floatx4 sf[8];
#pragma unroll
  for (int nt = 0; nt < 8; nt++) {
    bf16x8 bfrag = *(bf16x8*)&Kl[(nt * 16 + lm) * 40 + quad * 8];
    floatx4 z = {0.f, 0.f, 0.f, 0.f};
    sf[nt] = __builtin_amdgcn_mfma_f32_16x16x32_bf16(afrag, bfrag, z, 0, 0, 0);
  }
#pragma unroll
  for (int nt = 0; nt < 8; nt++) sf[nt] *= scale;
  float linv[4];
#pragma unroll
  for (int r = 0; r < 4; r++) {
    float mx = sf[0][r];
#pragma unroll
    for (int nt = 1; nt < 8; nt++) mx = fmaxf(mx, sf[nt][r]);
    mx = fmaxf(mx, __shfl_xor(mx, 1));
    mx = fmaxf(mx, __shfl_xor(mx, 2));
    mx = fmaxf(mx, __shfl_xor(mx, 4));
    mx = fmaxf(mx, __shfl_xor(mx, 8));
    float sum = 0.f;
#pragma unroll
    for (int nt = 0; nt < 8; nt++) {
      float p = __expf(sf[nt][r] - mx);
      sf[nt][r] = p;
      sum += p;
    }
    sum += __shfl_xor(sum, 1);
    sum += __shfl_xor(sum, 2);
    sum += __shfl_xor(sum, 4);
    sum += __shfl_xor(sum, 8);
    linv[r] = 1.f / sum;
  }
#pragma unroll
  for (int nt = 0; nt < 8; nt++)
#pragma unroll
    for (int r = 0; r < 4; r++)
      Pl[(wv * 16 + quad * 4 + r) * 136 + nt * 16 + lm] = f2bf(sf[nt][r]);

  floatx4 oacc[2] = {{0.f, 0.f, 0.f, 0.f}, {0.f, 0.f, 0.f, 0.f}};
#pragma unroll
  for (int kc = 0; kc < 4; kc++) {
    bf16x8 pf = *(bf16x8*)&Pl[(wv * 16 + lm) * 136 + kc * 32 + quad * 8];
#pragma unroll
    for (int nt2 = 0; nt2 < 2; nt2++) {
      bf16x8 vf = *(bf16x8*)&Vt[(nt2 * 16 + lm) * 136 + kc * 32 + quad * 8];
      oacc[nt2] = __builtin_amdgcn_mfma_f32_16x16x32_bf16(pf, vf, oacc[nt2], 0, 0, 0);
    }
  }
  // stage O+Q residual in Pl rows (wave-local), then coalesced int4 store
  short* Ol = Pl;
#pragma unroll
  for (int nt2 = 0; nt2 < 2; nt2++) {
#pragma unroll
    for (int r = 0; r < 4; r++) {
      int qrow = wv * 16 + quad * 4 + r;
      float q = bf2f(Ql[qrow * 40 + nt2 * 16 + lm]);
      Ol[qrow * 136 + nt2 * 16 + lm] = f2bf(q + oacc[nt2][r] * linv[r]);
    }
  }
  int rr = tid >> 2, seg = tid & 3;      // wave-local Ol rows
  size_t o = ((size_t)b * OBS + q0 + rr) * 128 + h * 32 + seg * 8;
  *(int4*)&O[o] = *(int4*)&Ol[rr * 136 + seg * 8];
}

// ---------------------------------------------------------------------------
// Kernel: fusedC — fc_o + residual Z update + next layer's K0/V0/Q1.
// grid 1024 (64 rows). Wk==null => last layer (no projections).
// R21: glds staging; each glds issued after the barrier freeing its dest
// (Wk0 moved post-B1 -> post-B2); 8 barriers unchanged.
// ---------------------------------------------------------------------------
__global__ __launch_bounds__(256, 3) void fusedC_kernel(
    const short* __restrict__ Ob, const short* __restrict__ Wo,
    const float* __restrict__ obias, const float* __restrict__ mk,
    const float* __restrict__ Zin, float* __restrict__ Zout,
    const short* __restrict__ Wk, const float* __restrict__ kbias,
    short* __restrict__ Kb,
    const short* __restrict__ Wv, const float* __restrict__ vbias,
    short* __restrict__ Vb,
    const short* __restrict__ Wq, const float* __restrict__ qbias,
    short* __restrict__ Qb) {
  __shared__ __align__(16) short Xl[64 * 128];
  __shared__ __align__(16) short WlA[64 * 128];
  __shared__ __align__(16) short WlB[64 * 128];
  int tid = threadIdx.x;
  int rb = blockIdx.x * 64;
  int wv = tid >> 6, lane = tid & 63, lm = lane & 15, quad = lane >> 4;

  stage_glds_h(WlA, Wo, tid);          // Wo0 -> WlA (dest fresh)
  bf16x8 afO[4];
  {
    const short* arow = Ob + (size_t)(rb + wv * 16 + lm) * 128;
#pragma unroll
    for (int kc = 0; kc < 4; kc++) {
      afO[kc] = *(const bf16x8*)&arow[kc * 32 + quad * 8];
      *(bf16x8*)&Xl[swz(wv * 16 + lm, kc * 32 + quad * 8)] = afO[kc];
    }
  }
  int row0 = wv * 16 + quad * 4;
  float mkv[4];
#pragma unroll
  for (int r = 0; r < 4; r++) mkv[r] = mk[rb + row0 + r];
  __syncthreads();   // B1: WlA(Wo0) landed + Xl(O) ready
  stage_glds_h(WlB, Wo + 8192, tid);   // Wo1 -> WlB (dest fresh)
  floatx4 acc[4];
  gemm4_s(WlA, afO, lm, quad, acc);
  // epilogue half 0 (cols 0..63): f = O + relu(acc+b); z = Zin + f*mk
#pragma unroll
  for (int nt = 0; nt < 4; nt++) {
    int col = nt * 16 + lm;
    float bn = obias[col];
#pragma unroll
    for (int r = 0; r < 4; r++) {
      int row = row0 + r;
      size_t g = (size_t)(rb + row) * 128 + col;
      float ov = bf2f(Xl[swz(row, col)]);
      float f = ov + fmaxf(acc[nt][r] + bn, 0.f);
      float zv = Zin[g] + f * mkv[r];
      Zout[g] = zv;
      Xl[swz(row, col)] = f2bf(zv);
    }
  }
  __syncthreads();   // B2: WlB(Wo1) landed; WlA reads done
  if (Wk) stage_glds_h(WlA, Wk, tid);  // Wk0 -> WlA (freed at B2)
  gemm4_s(WlB, afO, lm, quad, acc);
  // epilogue half 1 (cols 64..127)
#pragma unroll
  for (int nt = 0; nt < 4; nt++) {
    int col = 64 + nt * 16 + lm;
    float bn = obias[col];
#pragma unroll
    for (int r = 0; r < 4; r++) {
      int row = row0 + r;
      size_t g = (size_t)(rb + row) * 128 + col;
      float ov = bf2f(Xl[swz(row, col)]);
      float f = ov + fmaxf(acc[nt][r] + bn, 0.f);
      float zv = Zin[g] + f * mkv[r];
      Zout[g] = zv;
      Xl[swz(row, col)] = f2bf(zv);
    }
  }
  if (Wk == nullptr) return;
  bf16x8 af[4];
  load_af_s(Xl, wv, lm, quad, af);   // af = new-Z fragments (wave-local)
  __syncthreads();   // B3: WlA(Wk0) landed; WlB reads done
  stage_glds_h(WlB, Wk + 8192, tid);   // Wk1 -> WlB (freed at B3)
  gemm4_s(WlA, af, lm, quad, acc);
  store_sl4(Xl, acc, kbias, wv, lm, quad, 0);
  __syncthreads();   // B4: WlB(Wk1) landed; WlA reads done
  stage_glds_h(WlA, Wv, tid);          // Wv0 -> WlA
  gemm4_s(WlB, af, lm, quad, acc);
  store_sl4(Xl, acc, kbias, wv, lm, quad, 64);
  write_hs_s(Xl, Kb, rb, 12, tid);
  __syncthreads();   // B5: WlA(Wv0) landed
  stage_glds_h(WlB, Wv + 8192, tid);   // Wv1 -> WlB
  gemm4_s(WlA, af, lm, quad, acc);
  store_sl4(Xl, acc, vbias, wv, lm, quad, 0);
  __syncthreads();   // B6: WlB(Wv1) landed
  stage_glds_h(WlA, Wq, tid);          // Wq0 -> WlA
  gemm4_s(WlB, af, lm, quad, acc);
  store_sl4(Xl, acc, vbias, wv, lm, quad, 64);
  write_hs_s(Xl, Vb, rb, 12, tid);
  __syncthreads();   // B7: WlA(Wq0) landed
  stage_glds_h(WlB, Wq + 8192, tid);   // Wq1 -> WlB
  gemm4_s(WlA, af, lm, quad, acc);
  store_sl4(Xl, acc, qbias, wv, lm, quad, 0);
  __syncthreads();   // B8: WlB(Wq1) landed
  gemm4_s(WlB, af, lm, quad, acc);
  store_sl4(Xl, acc, qbias, wv, lm, quad, 64);
  write_hs_s(Xl, Qb, rb, 12, tid);
}

// ---------------------------------------------------------------------------
extern "C" void kernel_launch(void* const* d_in, const int* in_sizes, int n_in,
                              void* d_out, int out_size, void* d_ws,
                              size_t ws_size, hipStream_t stream) {
  const float* cx    = (const float*)d_in[0];
  const float* value = (const float*)d_in[1];
  const float* mask  = (const float*)d_in[2];
  const float* iff_w = (const float*)d_in[4];
  const float* iff_b = (const float*)d_in[5];
  const float* indp  = (const float*)d_in[6];
  const float* q0w = (const float*)d_in[7];  const float* q0b = (const float*)d_in[8];
  const float* k0w = (const float*)d_in[9];  const float* k0b = (const float*)d_in[10];
  const float* v0w = (const float*)d_in[11]; const float* v0b = (const float*)d_in[12];
  const float* o0w = (const float*)d_in[13]; const float* o0b = (const float*)d_in[14];
  const float* q1w = (const float*)d_in[15]; const float* q1b = (const float*)d_in[16];
  const float* k1w = (const float*)d_in[17]; const float* k1b = (const float*)d_in[18];
  const float* v1w = (const float*)d_in[19]; const float* v1b = (const float*)d_in[20];
  const float* o1w = (const float*)d_in[21]; const float* o1b = (const float*)d_in[22];

  char* ws = (char*)d_ws;
  short* Wt    = (short*)ws;  ws += (size_t)24 * 16384 * 2;
  int*   order = (int*)ws;    ws += (size_t)NBATCH * OBS * 4;
  float* mk_g  = (float*)ws;  ws += (size_t)NBATCH * OBS * 4;
  float* Z     = (float*)ws;  ws += (size_t)NBATCH * OBS * DK * 4;
  short* Qb    = (short*)ws;  ws += (size_t)NBATCH * OBS * DK * 2;
  short* Kb    = (short*)ws;  ws += (size_t)NBATCH * OBS * DK * 2;
  short* Vb    = (short*)ws;  ws += (size_t)NBATCH * OBS * DK * 2;
  short* Ob    = (short*)ws;  ws += (size_t)NBATCH * OBS * DK * 2;
  short* qh_b  = (short*)ws;  ws += (size_t)3 * 128 * DK * 2;
  short* khb   = (short*)ws;  ws += (size_t)NBATCH * NH * 128 * DH * 2;
  short* vhb   = (short*)ws;  ws += (size_t)NBATCH * NH * 128 * DH * 2;
  float* Opart = (float*)ws;  ws += (size_t)8 * 64 * 128 * 32 * 4;
  float* mpart = (float*)ws;  ws += (size_t)8 * 64 * 128 * 4;
  float* lpart = (float*)ws;  ws += (size_t)8 * 64 * 128 * 4;

  float* outZ  = (float*)d_out;
  float* outMk = outZ + (size_t)NBATCH * OBS * DK;

  prep_build_kernel<<<40, 1024, 0, stream>>>(q0w, k0w, v0w, o0w, q1w, k1w,
                                             v1w, o1w, Wt, mask, order, mk_g,
                                             outMk);

  const short* W[3][8];
  for (int l = 0; l < 3; l++)
    for (int wi = 0; wi < 8; wi++) W[l][wi] = Wt + (size_t)(l * 8 + wi) * 16384;

  fusedA_kernel<<<1030, 256, 0, stream>>>(
      order, mk_g, cx, value, iff_w, iff_b, Z,
      W[0][1], k0b, Kb, W[0][2], v0b, Vb, W[0][4], q1b, Qb,
      indp, Wt, q0b, qh_b);

  for (int l = 0; l < 3; l++) {
    attn1_kernel<<<dim3(64, 8), 256, 0, stream>>>(
        qh_b + (size_t)l * 16384, Kb, Vb, mk_g, Opart, mpart, lpart);
    fusedB_kernel<<<32, 1024, 0, stream>>>(
        Opart, mpart, lpart, qh_b + (size_t)l * 16384,
        W[l][3], o0b + (size_t)l * 128,
        W[l][5], k1b + (size_t)l * 128,
        W[l][6], v1b + (size_t)l * 128, khb, vhb);
    attn2_kernel<<<dim3(64, 64), 256, 0, stream>>>(Qb, khb, vhb, Ob);
    if (l < 2) {
      fusedC_kernel<<<1024, 256, 0, stream>>>(
          Ob, W[l][7], o1b + (size_t)l * 128, mk_g, Z, Z,
          W[l + 1][1], k0b + (size_t)(l + 1) * 128, Kb,
          W[l + 1][2], v0b + (size_t)(l + 1) * 128, Vb,
          W[l + 1][4], q1b + (size_t)(l + 1) * 128, Qb);
    } else {
      fusedC_kernel<<<1024, 256, 0, stream>>>(
          Ob, W[l][7], o1b + (size_t)l * 128, mk_g, Z, outZ,
          nullptr, nullptr, nullptr, nullptr, nullptr, nullptr,
          nullptr, nullptr, nullptr);
    }
  }
}